// Round 5
// baseline (1133.007 us; speedup 1.0000x reference)
//
#include <hip/hip_runtime.h>
#include <hip/hip_bf16.h>
#include <stdint.h>
#include <stddef.h>

#define NN 100000
#define NE 300000
#define FINDIM 128
#define HD 256
#define NG 4000
#define NLAYER 5
#define MPAD 100096   // 782*128, padded row count; pad rows kept == 0.0f always

typedef __attribute__((ext_vector_type(8))) short bf8;
typedef __attribute__((ext_vector_type(4))) float f4;

#define FENCE() __asm__ volatile("" ::: "memory")
#define WAITVM3() __asm__ volatile("s_waitcnt vmcnt(3)" ::: "memory")
#define WAITVM0() __asm__ volatile("s_waitcnt vmcnt(0)" ::: "memory")
#define WAITVM3L0() __asm__ volatile("s_waitcnt vmcnt(3) lgkmcnt(0)" ::: "memory")
#define WAITLGKM() __asm__ volatile("s_waitcnt lgkmcnt(0)" ::: "memory")
#define BARRIER() do { FENCE(); __builtin_amdgcn_s_barrier(); FENCE(); } while(0)

__device__ __forceinline__ unsigned short f2bf(float f){
  union { float f; unsigned u; } uf; uf.f = f;
  unsigned r = uf.u + 0x7fffu + ((uf.u >> 16) & 1u);
  return (unsigned short)(r >> 16);
}
__device__ __forceinline__ float bf2f(unsigned short h){
  union { unsigned u; float f; } uf; uf.u = ((unsigned)h) << 16; return uf.f;
}

__device__ __forceinline__ void gload16(const void* g, void* l){
  __builtin_amdgcn_global_load_lds((const __attribute__((address_space(1))) void*)g,
                                   (__attribute__((address_space(3))) void*)l, 16, 0, 0);
}

// ---------------- zero fill ----------------
__global__ void k_zero(int* __restrict__ p, int n){
  int i = blockIdx.x*256 + threadIdx.x;
  if(i < n) p[i] = 0;
}

// ---------------- CSR build ----------------
__global__ void k_count(const int* __restrict__ ei, int* __restrict__ counts){
  int e = blockIdx.x*256 + threadIdx.x;
  if(e < NE) atomicAdd(&counts[ei[NE + e]], 1);
}

__global__ void k_scan_partial(const int* __restrict__ counts, int* __restrict__ partials){
  __shared__ int sw[4];
  int b = blockIdx.x, t = threadIdx.x;
  int base = b*1024 + t*4;
  int s = 0;
  #pragma unroll
  for(int j=0;j<4;j++){ int i = base+j; if(i < NN) s += counts[i]; }
  #pragma unroll
  for(int d=1; d<64; d<<=1) s += __shfl_xor(s, d, 64);
  if((t & 63) == 0) sw[t>>6] = s;
  __syncthreads();
  if(t == 0) partials[b] = sw[0]+sw[1]+sw[2]+sw[3];
}

__global__ void k_scan_tot(int* __restrict__ partials, int* __restrict__ offsets, int nb){
  __shared__ int sm[128];
  int t = threadIdx.x;
  int v = (t < nb) ? partials[t] : 0;
  sm[t] = v; __syncthreads();
  for(int d=1; d<128; d<<=1){
    int x = 0;
    if(t >= d) x = sm[t-d];
    __syncthreads();
    sm[t] += x;
    __syncthreads();
  }
  if(t < nb) partials[t] = sm[t] - v;   // exclusive
  if(t == 127) offsets[NN] = sm[127];   // total == NE
}

__global__ void k_scan_final(const int* __restrict__ counts, const int* __restrict__ partials,
                             int* __restrict__ offsets, int* __restrict__ cursor){
  __shared__ int wsum[4];
  int b = blockIdx.x, t = threadIdx.x;
  int base = b*1024 + t*4;
  int c[4]; int ts = 0;
  #pragma unroll
  for(int j=0;j<4;j++){ int i = base+j; c[j] = (i < NN) ? counts[i] : 0; ts += c[j]; }
  int lane = t & 63;
  int inc = ts;
  #pragma unroll
  for(int d=1; d<64; d<<=1){ int x = __shfl_up(inc, d, 64); if(lane >= d) inc += x; }
  if(lane == 63) wsum[t>>6] = inc;
  __syncthreads();
  int woff = 0;
  for(int w2=0; w2<(t>>6); w2++) woff += wsum[w2];
  int excl = partials[b] + woff + inc - ts;
  #pragma unroll
  for(int j=0;j<4;j++){
    int i = base+j;
    if(i < NN){ offsets[i] = excl; cursor[i] = excl; excl += c[j]; }
  }
}

__global__ void k_fill(const int* __restrict__ ei, int* __restrict__ cursor, int* __restrict__ eidx){
  int e = blockIdx.x*256 + threadIdx.x;
  if(e < NE){
    int d = ei[NE + e];
    int pos = atomicAdd(&cursor[d], 1);
    eidx[pos] = ei[e];
  }
}

// ---------------- weight transpose/convert ----------------
__global__ void k_wt(const float* __restrict__ src, unsigned short* __restrict__ dst, int K, int Ncols){
  int l = blockIdx.y;
  size_t base = (size_t)l * K * Ncols;
  int i = blockIdx.x*256 + threadIdx.x;
  if(i < K*Ncols){
    int k = i / Ncols, n = i % Ncols;
    dst[base + (size_t)n*K + k] = f2bf(src[base + i]);
  }
}

// ---------------- pipelined GEMM: C[M,256](bf16) = act(A)[M,256] @ Bt^T + bias ----------------
// Block 128m x 256n, 8 waves x (64x64). K=256, 8 slabs of 32, double-buffered DMA.
// Pad rows [NN,MPAD) of A are 0; epilogue writes 0 there; stats sum raw acc (bias folded in bnfin).
template<int TRANS, bool RELUOUT, bool STATS>
__global__ __launch_bounds__(512, 4) void k_gemmp(
    const unsigned short* __restrict__ A, const unsigned short* __restrict__ Bt,
    const float* __restrict__ bias, const float* __restrict__ preS,
    const float* __restrict__ preT, unsigned short* __restrict__ C,
    float* __restrict__ stats)
{
  // per buffer: As 128x32 (4096 shorts) + Bs 256x32 (8192 shorts)
  __shared__ __align__(16) unsigned short Sm[2][12288];   // 48 KB
  __shared__ __align__(16) float SX[1024];                // 4 KB: SP during K-loop, stats after
  const int m0 = blockIdx.x*128;
  const int t = threadIdx.x;
  const int lane = t & 63, w = t >> 6;       // w: 0..7
  const int q = lane >> 4, ln = lane & 15;
  const int hs = (ln >> 1) & 3;
  const int srow = lane >> 2;
  const int cc = (lane & 3) ^ ((lane >> 3) & 3);
  const int mh = w >> 2, nq = w & 3;         // wave tile: (mh*64, nq*64)

  f4 acc[4][4];
  #pragma unroll
  for(int i=0;i<4;i++)
    #pragma unroll
    for(int j=0;j<4;j++) acc[i][j] = (f4){0.f,0.f,0.f,0.f};

  auto issue = [&](int s, int b){
    unsigned short* As = &Sm[b][0];
    unsigned short* Bs = &Sm[b][4096];
    const int kk = s*32;
    gload16(&A[(size_t)(m0 + w*16 + srow)*HD + kk + cc*8], &As[w*512]);
    #pragma unroll
    for(int j=0;j<2;j++)
      gload16(&Bt[(size_t)(w*32 + j*16 + srow)*HD + kk + cc*8], &Bs[w*1024 + j*512]);
  };

  if(TRANS){
    if(t < 256) SX[t] = preS[t];
    else        SX[t] = preT[t - 256];
  }
  issue(0, 0);
  issue(1, 1);
  WAITVM3L0();   // slab0's 3 DMAs landed; SX LDS writes drained
  BARRIER();

  #pragma unroll
  for(int s=0; s<8; s++){
    const int b = s & 1;
    const unsigned short* As = &Sm[b][0];
    const unsigned short* Bs = &Sm[b][4096];
    bf8 af[4], bb[4];
    #pragma unroll
    for(int mi=0;mi<4;mi++) af[mi] = *(const bf8*)&As[(mh*64 + mi*16 + ln)*32 + (q ^ hs)*8];
    #pragma unroll
    for(int ni=0;ni<4;ni++) bb[ni] = *(const bf8*)&Bs[(nq*64 + ni*16 + ln)*32 + (q ^ hs)*8];
    if(TRANS){
      f4 s0 = *(const f4*)&SX[s*32 + q*8];
      f4 s1 = *(const f4*)&SX[s*32 + q*8 + 4];
      f4 t0 = *(const f4*)&SX[256 + s*32 + q*8];
      f4 t1 = *(const f4*)&SX[256 + s*32 + q*8 + 4];
      float scv[8] = {s0.x,s0.y,s0.z,s0.w,s1.x,s1.y,s1.z,s1.w};
      float shv[8] = {t0.x,t0.y,t0.z,t0.w,t1.x,t1.y,t1.z,t1.w};
      #pragma unroll
      for(int mi=0;mi<4;mi++){
        #pragma unroll
        for(int j=0;j<8;j++){
          float v = bf2f((unsigned short)af[mi][j]);
          v = fmaxf(fmaf(scv[j], v, shv[j]), 0.f);
          af[mi][j] = (short)f2bf(v);
        }
      }
      if(m0 + 128 > NN){   // last block: zero transformed pad-row fragments
        #pragma unroll
        for(int mi=0;mi<4;mi++)
          if(m0 + mh*64 + mi*16 + ln >= NN) af[mi] = (bf8){0,0,0,0,0,0,0,0};
      }
    }
    WAITLGKM();          // all LDS reads of buf b complete
    BARRIER();           // every wave done with buf b -> safe to overwrite
    if(s + 2 < 8) issue(s + 2, b);
    #pragma unroll
    for(int mi=0;mi<4;mi++)
      #pragma unroll
      for(int ni=0;ni<4;ni++)
        acc[mi][ni] = __builtin_amdgcn_mfma_f32_16x16x32_bf16(af[mi], bb[ni], acc[mi][ni], 0, 0, 0);
    if(s + 1 < 8){
      if(s + 2 < 8) WAITVM3();   // slab s+1 landed; slab s+2's 3 loads stay in flight
      else          WAITVM0();
      BARRIER();
    }
  }

  // ---- stats: raw acc column sums (pad rows contribute exactly 0) ----
  if(STATS){
    #pragma unroll
    for(int ni=0;ni<4;ni++){
      float s = 0.f, ss = 0.f;
      #pragma unroll
      for(int mi=0;mi<4;mi++){
        #pragma unroll
        for(int r=0;r<4;r++){
          float v = acc[mi][ni][r];
          s += v; ss = fmaf(v, v, ss);
        }
      }
      s  += __shfl_xor(s, 16, 64);  s  += __shfl_xor(s, 32, 64);
      ss += __shfl_xor(ss, 16, 64); ss += __shfl_xor(ss, 32, 64);
      if(q == 0){
        int gn = nq*64 + ni*16 + ln;
        SX[mh*512 + gn]       = s;    // plain store: (mh, col) unique per writer
        SX[mh*512 + 256 + gn] = ss;
      }
    }
    __syncthreads();
    atomicAdd(&stats[t < 512 ? t : 0], 0.f);  // no-op shape keeper (t always < 512)
    {
      float v = SX[t] + SX[512 + t];
      atomicAdd(&stats[t], v);
    }
  }

  // ---- coalesced store via per-wave LDS scratch (Sm reuse safe: all reads drained) ----
  unsigned short* wsc = &Sm[0][0] + w*1152;   // 16 rows x 72
  #pragma unroll
  for(int mi=0;mi<4;mi++){
    #pragma unroll
    for(int ni=0;ni<4;ni++){
      float b = bias[nq*64 + ni*16 + ln];
      #pragma unroll
      for(int r=0;r<4;r++){
        int gm = m0 + mh*64 + mi*16 + q*4 + r;
        float v = acc[mi][ni][r] + b;
        if(RELUOUT) v = fmaxf(v, 0.f);
        if(gm >= NN) v = 0.f;          // keep pad rows exactly zero
        wsc[(q*4 + r)*72 + ni*16 + ln] = f2bf(v);
      }
    }
    int lrow = lane >> 2;
    int gm = m0 + mh*64 + mi*16 + lrow;
    int ch = lane & 3;
    uint4 u0 = *(const uint4*)&wsc[lrow*72 + ch*8];
    uint4 u1 = *(const uint4*)&wsc[lrow*72 + (ch+4)*8];
    *(uint4*)&C[(size_t)gm*HD + nq*64 + ch*8]     = u0;   // note: nq*64 spans 64 cols; ch covers 8*8=64
    *(uint4*)&C[(size_t)gm*HD + nq*64 + (ch+4)*8] = u1;
  }
}

// ---------------- input projection GEMM (f32 A, K=128), 128x256 tile, single-buffered ----------------
__global__ __launch_bounds__(512, 4) void k_gemm_in(
    const float* __restrict__ A, const unsigned short* __restrict__ Bt,
    const float* __restrict__ bias, unsigned short* __restrict__ C)
{
  const int K = FINDIM;
  __shared__ __align__(16) unsigned short As[128*32];   // 8 KB
  __shared__ __align__(16) unsigned short Bs[256*32];   // 16 KB
  __shared__ __align__(16) unsigned short Cs[8*16*72];  // 18 KB
  const int m0 = blockIdx.x*128;
  const int t = threadIdx.x;
  const int lane = t & 63, w = t >> 6;
  const int q = lane >> 4, ln = lane & 15;
  const int hs = (ln >> 1) & 3;
  const int srow = lane >> 2;
  const int cc = (lane & 3) ^ ((lane >> 3) & 3);
  const int mh = w >> 2, nq = w & 3;
  const int mr = t >> 2;
  const int mc = (t & 3) ^ ((t >> 3) & 3);

  f4 acc[4][4];
  #pragma unroll
  for(int i=0;i<4;i++)
    #pragma unroll
    for(int j=0;j<4;j++) acc[i][j] = (f4){0.f,0.f,0.f,0.f};

  for(int kk=0; kk<K; kk+=32){
    int gm = m0 + mr;
    f4 v0 = (f4){0.f,0.f,0.f,0.f}, v1 = (f4){0.f,0.f,0.f,0.f};
    if(gm < NN){
      v0 = *(const f4*)&A[(size_t)gm*K + kk + mc*8];
      v1 = *(const f4*)&A[(size_t)gm*K + kk + mc*8 + 4];
    }
    ushort4 a0, a1;
    a0.x = f2bf(v0.x); a0.y = f2bf(v0.y); a0.z = f2bf(v0.z); a0.w = f2bf(v0.w);
    a1.x = f2bf(v1.x); a1.y = f2bf(v1.y); a1.z = f2bf(v1.z); a1.w = f2bf(v1.w);
    *(ushort4*)&As[t*8]     = a0;
    *(ushort4*)&As[t*8 + 4] = a1;
    #pragma unroll
    for(int j=0;j<2;j++)
      gload16(&Bt[(size_t)(w*32 + j*16 + srow)*K + kk + cc*8], &Bs[w*1024 + j*512]);
    __syncthreads();

    bf8 af[4], bb[4];
    #pragma unroll
    for(int mi=0;mi<4;mi++) af[mi] = *(const bf8*)&As[(mh*64 + mi*16 + ln)*32 + (q ^ hs)*8];
    #pragma unroll
    for(int ni=0;ni<4;ni++) bb[ni] = *(const bf8*)&Bs[(nq*64 + ni*16 + ln)*32 + (q ^ hs)*8];
    #pragma unroll
    for(int mi=0;mi<4;mi++)
      #pragma unroll
      for(int ni=0;ni<4;ni++)
        acc[mi][ni] = __builtin_amdgcn_mfma_f32_16x16x32_bf16(af[mi], bb[ni], acc[mi][ni], 0, 0, 0);
    __syncthreads();
  }

  unsigned short* wsc = &Cs[w*1152];
  #pragma unroll
  for(int mi=0;mi<4;mi++){
    #pragma unroll
    for(int ni=0;ni<4;ni++){
      float b = bias[nq*64 + ni*16 + ln];
      #pragma unroll
      for(int r=0;r<4;r++){
        int gm = m0 + mh*64 + mi*16 + q*4 + r;
        float v = fmaxf(acc[mi][ni][r] + b, 0.f);
        if(gm >= NN) v = 0.f;
        wsc[(q*4 + r)*72 + ni*16 + ln] = f2bf(v);
      }
    }
    int lrow = lane >> 2;
    int gm = m0 + mh*64 + mi*16 + lrow;
    int ch = lane & 3;
    uint4 u0 = *(const uint4*)&wsc[lrow*72 + ch*8];
    uint4 u1 = *(const uint4*)&wsc[lrow*72 + (ch+4)*8];
    *(uint4*)&C[(size_t)gm*HD + nq*64 + ch*8]     = u0;
    *(uint4*)&C[(size_t)gm*HD + nq*64 + (ch+4)*8] = u1;
  }
}

// ---------------- BN finalize (bias folded here: stats are bias-free raw sums) ----------------
__global__ void k_bnfin(const float* __restrict__ cs, const float* __restrict__ bias,
                        const float* __restrict__ g, const float* __restrict__ be,
                        float* __restrict__ sc, float* __restrict__ sh){
  int c = threadIdx.x;
  float m0 = cs[c] * (1.0f/NN);
  float mean = m0 + bias[c];
  float var  = cs[HD + c] * (1.0f/NN) - m0*m0;
  float s = g[c] * rsqrtf(var + 1e-5f);
  sc[c] = s;
  sh[c] = be[c] - mean*s;
}

// ---------------- aggregation ----------------
__device__ __forceinline__ f4 act4(ushort4 uv, f4 s4, f4 t4, int ident){
  f4 u;
  u.x = bf2f(uv.x); u.y = bf2f(uv.y); u.z = bf2f(uv.z); u.w = bf2f(uv.w);
  if(!ident){
    u.x = fmaxf(fmaf(s4.x, u.x, t4.x), 0.f);
    u.y = fmaxf(fmaf(s4.y, u.y, t4.y), 0.f);
    u.z = fmaxf(fmaf(s4.z, u.z, t4.z), 0.f);
    u.w = fmaxf(fmaf(s4.w, u.w, t4.w), 0.f);
  }
  return u;
}

__global__ __launch_bounds__(256) void k_agg(const unsigned short* __restrict__ src,
    unsigned short* __restrict__ dst,
    const int* __restrict__ offs, const int* __restrict__ eidx,
    const float* __restrict__ eps, int l,
    const float* __restrict__ sc, const float* __restrict__ sh, int ident)
{
  int wv = threadIdx.x >> 6;
  int n = blockIdx.x*4 + wv;
  if(n >= NN) return;
  int lane = threadIdx.x & 63;
  int c = lane << 2;
  f4 s4 = (f4){0.f,0.f,0.f,0.f}, t4 = (f4){0.f,0.f,0.f,0.f};
  if(!ident){ s4 = *(const f4*)(sc + c); t4 = *(const f4*)(sh + c); }
  float ep = 1.f + eps[l];
  f4 a = act4(*(const ushort4*)(src + (size_t)n*HD + c), s4, t4, ident);
  f4 acc;
  acc.x = ep*a.x; acc.y = ep*a.y; acc.z = ep*a.z; acc.w = ep*a.w;
  int lo = offs[n], hi = offs[n+1];
  for(int base = lo; base < hi; base += 64){
    int rem = hi - base; if(rem > 64) rem = 64;
    int idx = 0;
    if(base + lane < hi) idx = eidx[base + lane];
    int j = 0;
    for(; j + 4 <= rem; j += 4){
      int s0 = __shfl(idx, j, 64),   s1 = __shfl(idx, j+1, 64);
      int s2 = __shfl(idx, j+2, 64), s3 = __shfl(idx, j+3, 64);
      ushort4 u0 = *(const ushort4*)(src + (size_t)s0*HD + c);
      ushort4 u1 = *(const ushort4*)(src + (size_t)s1*HD + c);
      ushort4 u2 = *(const ushort4*)(src + (size_t)s2*HD + c);
      ushort4 u3 = *(const ushort4*)(src + (size_t)s3*HD + c);
      f4 a0 = act4(u0, s4, t4, ident), a1 = act4(u1, s4, t4, ident);
      f4 a2 = act4(u2, s4, t4, ident), a3 = act4(u3, s4, t4, ident);
      acc.x += (a0.x + a1.x) + (a2.x + a3.x);
      acc.y += (a0.y + a1.y) + (a2.y + a3.y);
      acc.z += (a0.z + a1.z) + (a2.z + a3.z);
      acc.w += (a0.w + a1.w) + (a2.w + a3.w);
    }
    for(; j < rem; j++){
      int s0 = __shfl(idx, j, 64);
      f4 a0 = act4(*(const ushort4*)(src + (size_t)s0*HD + c), s4, t4, ident);
      acc.x += a0.x; acc.y += a0.y; acc.z += a0.z; acc.w += a0.w;
    }
  }
  ushort4 o;
  o.x = f2bf(acc.x); o.y = f2bf(acc.y); o.z = f2bf(acc.z); o.w = f2bf(acc.w);
  *(ushort4*)(dst + (size_t)n*HD + c) = o;
}

// ---------------- pooling ----------------
__device__ __forceinline__ int lowb(const int* __restrict__ arr, int n, int key){
  int lo = 0, hi = n;
  while(lo < hi){ int mid = (lo + hi) >> 1; if(arr[mid] < key) lo = mid + 1; else hi = mid; }
  return lo;
}

__global__ __launch_bounds__(256) void k_pool(const unsigned short* __restrict__ src,
    const int* __restrict__ batch,
    const float* __restrict__ sc, const float* __restrict__ sh, float* __restrict__ pooled)
{
  int wv = threadIdx.x >> 6;
  int g = blockIdx.x*4 + wv;
  if(g >= NG) return;
  int lane = threadIdx.x & 63;
  int c = lane << 2;
  int lo = lowb(batch, NN, g);
  int hi = lowb(batch, NN, g+1);
  f4 s4 = *(const f4*)(sc + c);
  f4 t4 = *(const f4*)(sh + c);
  f4 acc = (f4){0.f,0.f,0.f,0.f};
  for(int n=lo; n<hi; n++){
    ushort4 uv = *(const ushort4*)(src + (size_t)n*HD + c);
    acc.x += fmaxf(fmaf(s4.x, bf2f(uv.x), t4.x), 0.f);
    acc.y += fmaxf(fmaf(s4.y, bf2f(uv.y), t4.y), 0.f);
    acc.z += fmaxf(fmaf(s4.z, bf2f(uv.z), t4.z), 0.f);
    acc.w += fmaxf(fmaf(s4.w, bf2f(uv.w), t4.w), 0.f);
  }
  float inv = 1.0f / fmaxf((float)(hi - lo), 1.0f);
  acc.x *= inv; acc.y *= inv; acc.z *= inv; acc.w *= inv;
  *(f4*)(pooled + (size_t)g*HD + c) = acc;
}

// ---------------- head ----------------
__global__ __launch_bounds__(128) void k_head(const float* __restrict__ pooled,
    const float* __restrict__ W1, const float* __restrict__ b1,
    const float* __restrict__ W2, const float* __restrict__ b2, float* __restrict__ out)
{
  __shared__ float p[HD];
  __shared__ float red[2];
  int g = blockIdx.x, t = threadIdx.x;
  if(t < 64) *(f4*)&p[t*4] = *(const f4*)(pooled + (size_t)g*HD + t*4);
  __syncthreads();
  float s = b1[t];
  for(int k=0;k<HD;k++) s = fmaf(p[k], W1[k*128 + t], s);
  float o = fmaxf(s, 0.f) * W2[t];
  #pragma unroll
  for(int d=1; d<64; d<<=1) o += __shfl_xor(o, d, 64);
  if((t & 63) == 0) red[t>>6] = o;
  __syncthreads();
  if(t == 0) out[g] = red[0] + red[1] + b2[0];
}

// ---------------- launch ----------------
extern "C" void kernel_launch(void* const* d_in, const int* in_sizes, int n_in,
                              void* d_out, int out_size, void* d_ws, size_t ws_size,
                              hipStream_t stream) {
  const float* x    = (const float*)d_in[0];
  const int*   ei   = (const int*)  d_in[1];
  const int*   bat  = (const int*)  d_in[2];
  const float* inW  = (const float*)d_in[3];
  const float* inb  = (const float*)d_in[4];
  const float* W1   = (const float*)d_in[5];
  const float* b1   = (const float*)d_in[6];
  const float* g1   = (const float*)d_in[7];
  const float* be1  = (const float*)d_in[8];
  const float* W2   = (const float*)d_in[9];
  const float* b2   = (const float*)d_in[10];
  const float* g2   = (const float*)d_in[11];
  const float* be2  = (const float*)d_in[12];
  const float* eps  = (const float*)d_in[13];
  const float* hW1  = (const float*)d_in[14];
  const float* hb1  = (const float*)d_in[15];
  const float* hW2  = (const float*)d_in[16];
  const float* hb2  = (const float*)d_in[17];
  float* out = (float*)d_out;

  char* p = (char*)d_ws;
  auto alloc = [&](size_t bytes)->char*{
    char* r = p; p += (bytes + 255) & ~(size_t)255; return r;
  };
  unsigned short* B0 = (unsigned short*)alloc((size_t)MPAD*HD*2);
  unsigned short* B1 = (unsigned short*)alloc((size_t)MPAD*HD*2);
  unsigned short* Wtin = (unsigned short*)alloc((size_t)FINDIM*HD*2);
  unsigned short* Wt1  = (unsigned short*)alloc((size_t)NLAYER*HD*HD*2);
  unsigned short* Wt2  = (unsigned short*)alloc((size_t)NLAYER*HD*HD*2);
  int* counts  = (int*)alloc((size_t)NN*4);
  int* offsets = (int*)alloc((size_t)(NN+1)*4);
  int* cursor  = (int*)alloc((size_t)NN*4);
  int* eidx    = (int*)alloc((size_t)NE*4);
  int* partials= (int*)alloc(128*4);
  float* cs    = (float*)alloc(4*HD*4);
  float* bnp   = (float*)alloc(4*HD*4);
  float* pooled= (float*)alloc((size_t)NG*HD*4);

  // CSR build
  k_zero<<<(NN+255)/256, 256, 0, stream>>>(counts, NN);
  k_count<<<(NE+255)/256, 256, 0, stream>>>(ei, counts);
  int nb = (NN + 1023)/1024;
  k_scan_partial<<<nb, 256, 0, stream>>>(counts, partials);
  k_scan_tot<<<1, 128, 0, stream>>>(partials, offsets, nb);
  k_scan_final<<<nb, 256, 0, stream>>>(counts, partials, offsets, cursor);
  k_fill<<<(NE+255)/256, 256, 0, stream>>>(ei, cursor, eidx);

  // weights -> bf16 [n][k]
  k_wt<<<dim3((FINDIM*HD+255)/256, 1), 256, 0, stream>>>(inW, Wtin, FINDIM, HD);
  k_wt<<<dim3((HD*HD+255)/256, NLAYER), 256, 0, stream>>>(W1, Wt1, HD, HD);
  k_wt<<<dim3((HD*HD+255)/256, NLAYER), 256, 0, stream>>>(W2, Wt2, HD, HD);

  // zero pad rows of B1 once (B0's pad established by gemm_in epilogue)
  {
    int padInts = (MPAD - NN) * HD / 2;   // shorts/2
    k_zero<<<(padInts+255)/256, 256, 0, stream>>>((int*)(B1 + (size_t)NN*HD), padInts);
  }

  const int MB = MPAD/128;  // 782 m-blocks
  k_gemm_in<<<MB, 512, 0, stream>>>(x, Wtin, inb, B0);

  float* sc1 = bnp, *sh1 = bnp + HD, *sc2 = bnp + 2*HD, *sh2 = bnp + 3*HD;
  unsigned short* hbuf = B0;
  unsigned short* tbuf = B1;
  for(int l=0; l<NLAYER; l++){
    k_zero<<<4, 256, 0, stream>>>((int*)cs, 4*HD);
    k_agg<<<(NN+3)/4, 256, 0, stream>>>(hbuf, tbuf, offsets, eidx, eps, l, sc2, sh2, l==0 ? 1 : 0);
    k_gemmp<0, false, true><<<MB, 512, 0, stream>>>(tbuf, Wt1 + (size_t)l*HD*HD, b1 + l*HD,
                                                    nullptr, nullptr, hbuf, cs);
    k_bnfin<<<1, HD, 0, stream>>>(cs, b1 + l*HD, g1 + l*HD, be1 + l*HD, sc1, sh1);
    k_gemmp<1, false, true><<<MB, 512, 0, stream>>>(hbuf, Wt2 + (size_t)l*HD*HD, b2 + l*HD,
                                                    sc1, sh1, tbuf, cs + 2*HD);
    k_bnfin<<<1, HD, 0, stream>>>(cs + 2*HD, b2 + l*HD, g2 + l*HD, be2 + l*HD, sc2, sh2);
    unsigned short* tmp = hbuf; hbuf = tbuf; tbuf = tmp;
  }

  k_pool<<<(NG+3)/4, 256, 0, stream>>>(hbuf, bat, sc2, sh2, pooled);
  k_head<<<NG, 128, 0, stream>>>(pooled, hW1, hb1, hW2, hb2, out);
}

// Round 6
// 1086.788 us; speedup vs baseline: 1.0425x; 1.0425x over previous
//
#include <hip/hip_runtime.h>
#include <hip/hip_bf16.h>
#include <stdint.h>
#include <stddef.h>

#define NN 100000
#define NE 300000
#define FINDIM 128
#define HD 256
#define NG 4000
#define NLAYER 5
#define MPAD 100096   // 1564*64, padded row count; pad rows kept == 0.0f always

typedef __attribute__((ext_vector_type(8))) short bf8;
typedef __attribute__((ext_vector_type(4))) float f4;

__device__ __forceinline__ unsigned short f2bf(float f){
  union { float f; unsigned u; } uf; uf.f = f;
  unsigned r = uf.u + 0x7fffu + ((uf.u >> 16) & 1u);
  return (unsigned short)(r >> 16);
}
__device__ __forceinline__ float bf2f(unsigned short h){
  union { unsigned u; float f; } uf; uf.u = ((unsigned)h) << 16; return uf.f;
}

__device__ __forceinline__ void gload16(const void* g, void* l){
  __builtin_amdgcn_global_load_lds((const __attribute__((address_space(1))) void*)g,
                                   (__attribute__((address_space(3))) void*)l, 16, 0, 0);
}

// ---------------- zero fill ----------------
__global__ void k_zero(int* __restrict__ p, int n){
  int i = blockIdx.x*256 + threadIdx.x;
  if(i < n) p[i] = 0;
}

// ---------------- CSR build ----------------
__global__ void k_count(const int* __restrict__ ei, int* __restrict__ counts){
  int e = blockIdx.x*256 + threadIdx.x;
  if(e < NE) atomicAdd(&counts[ei[NE + e]], 1);
}

__global__ void k_scan_partial(const int* __restrict__ counts, int* __restrict__ partials){
  __shared__ int sw[4];
  int b = blockIdx.x, t = threadIdx.x;
  int base = b*1024 + t*4;
  int s = 0;
  #pragma unroll
  for(int j=0;j<4;j++){ int i = base+j; if(i < NN) s += counts[i]; }
  #pragma unroll
  for(int d=1; d<64; d<<=1) s += __shfl_xor(s, d, 64);
  if((t & 63) == 0) sw[t>>6] = s;
  __syncthreads();
  if(t == 0) partials[b] = sw[0]+sw[1]+sw[2]+sw[3];
}

__global__ void k_scan_tot(int* __restrict__ partials, int* __restrict__ offsets, int nb){
  __shared__ int sm[128];
  int t = threadIdx.x;
  int v = (t < nb) ? partials[t] : 0;
  sm[t] = v; __syncthreads();
  for(int d=1; d<128; d<<=1){
    int x = 0;
    if(t >= d) x = sm[t-d];
    __syncthreads();
    sm[t] += x;
    __syncthreads();
  }
  if(t < nb) partials[t] = sm[t] - v;   // exclusive
  if(t == 127) offsets[NN] = sm[127];   // total == NE
}

__global__ void k_scan_final(const int* __restrict__ counts, const int* __restrict__ partials,
                             int* __restrict__ offsets, int* __restrict__ cursor){
  __shared__ int wsum[4];
  int b = blockIdx.x, t = threadIdx.x;
  int base = b*1024 + t*4;
  int c[4]; int ts = 0;
  #pragma unroll
  for(int j=0;j<4;j++){ int i = base+j; c[j] = (i < NN) ? counts[i] : 0; ts += c[j]; }
  int lane = t & 63;
  int inc = ts;
  #pragma unroll
  for(int d=1; d<64; d<<=1){ int x = __shfl_up(inc, d, 64); if(lane >= d) inc += x; }
  if(lane == 63) wsum[t>>6] = inc;
  __syncthreads();
  int woff = 0;
  for(int w2=0; w2<(t>>6); w2++) woff += wsum[w2];
  int excl = partials[b] + woff + inc - ts;
  #pragma unroll
  for(int j=0;j<4;j++){
    int i = base+j;
    if(i < NN){ offsets[i] = excl; cursor[i] = excl; excl += c[j]; }
  }
}

__global__ void k_fill(const int* __restrict__ ei, int* __restrict__ cursor, int* __restrict__ eidx){
  int e = blockIdx.x*256 + threadIdx.x;
  if(e < NE){
    int d = ei[NE + e];
    int pos = atomicAdd(&cursor[d], 1);
    eidx[pos] = ei[e];
  }
}

// ---------------- weight transpose/convert ----------------
__global__ void k_wt(const float* __restrict__ src, unsigned short* __restrict__ dst, int K, int Ncols){
  int l = blockIdx.y;
  size_t base = (size_t)l * K * Ncols;
  int i = blockIdx.x*256 + threadIdx.x;
  if(i < K*Ncols){
    int k = i / Ncols, n = i % Ncols;
    dst[base + (size_t)n*K + k] = f2bf(src[base + i]);
  }
}

// ---------------- GEMM: C[M,256](bf16) = act(A)[M,256] @ Bt^T + bias ----------------
// Block 64m x 256n, 4 waves x (64x64). A: LDS double-buffered DMA (4 KB/slab).
// B: direct global->VGPR fragment loads (L2-resident weight, no LDS staging).
// Pad rows [NN,MPAD) of A are 0; epilogue writes 0 there; stats = raw col sums (bias in bnfin).
template<int TRANS, bool RELUOUT, bool STATS>
__global__ __launch_bounds__(256, 3) void k_gemmp(
    const unsigned short* __restrict__ A, const unsigned short* __restrict__ Bt,
    const float* __restrict__ bias, const float* __restrict__ preS,
    const float* __restrict__ preT, unsigned short* __restrict__ C,
    float* __restrict__ stats)
{
  __shared__ __align__(16) unsigned short As[2][2048];   // 2 x (64 rows x 32 k)  = 8 KB
  __shared__ __align__(16) unsigned short Cs[4*1152];    // epilogue scratch 9 KB
  __shared__ __align__(16) float SP[512];                // scale/shift for TRANS
  const int m0 = blockIdx.x*64;
  const int t = threadIdx.x;
  const int lane = t & 63, w = t >> 6;
  const int q = lane >> 4, ln = lane & 15;
  const int hs = (ln >> 1) & 3;
  const int srow = lane >> 2;
  const int cc = (lane & 3) ^ ((lane >> 3) & 3);

  f4 acc[4][4];
  #pragma unroll
  for(int i=0;i<4;i++)
    #pragma unroll
    for(int j=0;j<4;j++) acc[i][j] = (f4){0.f,0.f,0.f,0.f};

  // per-lane B fragment base: row (w*64 + ln), k-chunk q*8
  const unsigned short* bp = Bt + (size_t)(w*64 + ln)*HD + q*8;

  auto issueA = [&](int s, int b){
    gload16(&A[(size_t)(m0 + w*16 + srow)*HD + s*32 + cc*8], &As[b][w*512]);
  };

  if(TRANS){ SP[t] = preS[t]; SP[256 + t] = preT[t]; }
  issueA(0, 0);

  #pragma unroll
  for(int s=0; s<8; s++){
    __syncthreads();               // A(s) DMA landed (syncthreads drains vmcnt); buf[(s+1)&1] free
    if(s < 7) issueA(s+1, (s+1)&1);
    const unsigned short* Ab = &As[s&1][0];
    bf8 af[4], bb[4];
    #pragma unroll
    for(int mi=0;mi<4;mi++) af[mi] = *(const bf8*)&Ab[(mi*16 + ln)*32 + (q ^ hs)*8];
    #pragma unroll
    for(int ni=0;ni<4;ni++) bb[ni] = *(const bf8*)(bp + (size_t)ni*16*HD + s*32);
    if(TRANS){
      f4 s0 = *(const f4*)&SP[s*32 + q*8];
      f4 s1 = *(const f4*)&SP[s*32 + q*8 + 4];
      f4 t0 = *(const f4*)&SP[256 + s*32 + q*8];
      f4 t1 = *(const f4*)&SP[256 + s*32 + q*8 + 4];
      float scv[8] = {s0.x,s0.y,s0.z,s0.w,s1.x,s1.y,s1.z,s1.w};
      float shv[8] = {t0.x,t0.y,t0.z,t0.w,t1.x,t1.y,t1.z,t1.w};
      #pragma unroll
      for(int mi=0;mi<4;mi++){
        #pragma unroll
        for(int j=0;j<8;j++){
          float v = bf2f((unsigned short)af[mi][j]);
          v = fmaxf(fmaf(scv[j], v, shv[j]), 0.f);
          af[mi][j] = (short)f2bf(v);
        }
      }
      if(m0 + 64 > NN){   // last blocks: zero transformed pad-row fragments
        #pragma unroll
        for(int mi=0;mi<4;mi++)
          if(m0 + mi*16 + ln >= NN) af[mi] = (bf8){0,0,0,0,0,0,0,0};
      }
    }
    #pragma unroll
    for(int mi=0;mi<4;mi++)
      #pragma unroll
      for(int ni=0;ni<4;ni++)
        acc[mi][ni] = __builtin_amdgcn_mfma_f32_16x16x32_bf16(af[mi], bb[ni], acc[mi][ni], 0, 0, 0);
  }

  // ---- stats: raw acc column sums (pad rows contribute exactly 0) ----
  if(STATS){
    #pragma unroll
    for(int ni=0;ni<4;ni++){
      float s = 0.f, ss = 0.f;
      #pragma unroll
      for(int mi=0;mi<4;mi++){
        #pragma unroll
        for(int r=0;r<4;r++){
          float v = acc[mi][ni][r];
          s += v; ss = fmaf(v, v, ss);
        }
      }
      s  += __shfl_xor(s, 16, 64);  s  += __shfl_xor(s, 32, 64);
      ss += __shfl_xor(ss, 16, 64); ss += __shfl_xor(ss, 32, 64);
      if(q == 0){
        int gn = w*64 + ni*16 + ln;
        atomicAdd(&stats[gn], s);
        atomicAdd(&stats[HD + gn], ss);
      }
    }
  }

  // ---- coalesced store via per-wave LDS scratch ----
  unsigned short* wsc = &Cs[w*1152];   // 16 rows x 72
  #pragma unroll
  for(int mi=0;mi<4;mi++){
    #pragma unroll
    for(int ni=0;ni<4;ni++){
      float b = bias[w*64 + ni*16 + ln];
      #pragma unroll
      for(int r=0;r<4;r++){
        int gm = m0 + mi*16 + q*4 + r;
        float v = acc[mi][ni][r] + b;
        if(RELUOUT) v = fmaxf(v, 0.f);
        if(gm >= NN) v = 0.f;          // keep pad rows exactly zero
        wsc[(q*4 + r)*72 + ni*16 + ln] = f2bf(v);
      }
    }
    int lrow = lane >> 2;
    int gm = m0 + mi*16 + lrow;
    int ch = lane & 3;
    uint4 u0 = *(const uint4*)&wsc[lrow*72 + ch*8];
    uint4 u1 = *(const uint4*)&wsc[lrow*72 + (ch+4)*8];
    *(uint4*)&C[(size_t)gm*HD + w*64 + ch*8]     = u0;
    *(uint4*)&C[(size_t)gm*HD + w*64 + (ch+4)*8] = u1;
  }
}

// ---------------- input projection GEMM (f32 A, K=128): A manual-staged, B direct ----------------
__global__ __launch_bounds__(256, 3) void k_gemm_in(
    const float* __restrict__ A, const unsigned short* __restrict__ Bt,
    const float* __restrict__ bias, unsigned short* __restrict__ C)
{
  const int K = FINDIM;
  __shared__ __align__(16) unsigned short As[64*32];    // 4 KB
  __shared__ __align__(16) unsigned short Cs[4*1152];   // 9 KB
  const int m0 = blockIdx.x*64;
  const int t = threadIdx.x;
  const int lane = t & 63, w = t >> 6;
  const int q = lane >> 4, ln = lane & 15;
  const int hs = (ln >> 1) & 3;
  const int mr = t >> 2;
  const int mc = (t & 3) ^ ((t >> 3) & 3);

  f4 acc[4][4];
  #pragma unroll
  for(int i=0;i<4;i++)
    #pragma unroll
    for(int j=0;j<4;j++) acc[i][j] = (f4){0.f,0.f,0.f,0.f};

  const unsigned short* bp = Bt + (size_t)(w*64 + ln)*K + q*8;

  for(int kk=0; kk<K; kk+=32){
    int gm = m0 + mr;
    f4 v0 = (f4){0.f,0.f,0.f,0.f}, v1 = (f4){0.f,0.f,0.f,0.f};
    if(gm < NN){
      v0 = *(const f4*)&A[(size_t)gm*K + kk + mc*8];
      v1 = *(const f4*)&A[(size_t)gm*K + kk + mc*8 + 4];
    }
    ushort4 a0, a1;
    a0.x = f2bf(v0.x); a0.y = f2bf(v0.y); a0.z = f2bf(v0.z); a0.w = f2bf(v0.w);
    a1.x = f2bf(v1.x); a1.y = f2bf(v1.y); a1.z = f2bf(v1.z); a1.w = f2bf(v1.w);
    *(ushort4*)&As[t*8]     = a0;
    *(ushort4*)&As[t*8 + 4] = a1;
    __syncthreads();

    bf8 af[4], bb[4];
    #pragma unroll
    for(int mi=0;mi<4;mi++) af[mi] = *(const bf8*)&As[(mi*16 + ln)*32 + (q ^ hs)*8];
    #pragma unroll
    for(int ni=0;ni<4;ni++) bb[ni] = *(const bf8*)(bp + (size_t)ni*16*K + kk);
    #pragma unroll
    for(int mi=0;mi<4;mi++)
      #pragma unroll
      for(int ni=0;ni<4;ni++)
        acc[mi][ni] = __builtin_amdgcn_mfma_f32_16x16x32_bf16(af[mi], bb[ni], acc[mi][ni], 0, 0, 0);
    __syncthreads();
  }

  unsigned short* wsc = &Cs[w*1152];
  #pragma unroll
  for(int mi=0;mi<4;mi++){
    #pragma unroll
    for(int ni=0;ni<4;ni++){
      float b = bias[w*64 + ni*16 + ln];
      #pragma unroll
      for(int r=0;r<4;r++){
        int gm = m0 + mi*16 + q*4 + r;
        float v = fmaxf(acc[mi][ni][r] + b, 0.f);
        if(gm >= NN) v = 0.f;
        wsc[(q*4 + r)*72 + ni*16 + ln] = f2bf(v);
      }
    }
    int lrow = lane >> 2;
    int gm = m0 + mi*16 + lrow;
    int ch = lane & 3;
    uint4 u0 = *(const uint4*)&wsc[lrow*72 + ch*8];
    uint4 u1 = *(const uint4*)&wsc[lrow*72 + (ch+4)*8];
    *(uint4*)&C[(size_t)gm*HD + w*64 + ch*8]     = u0;
    *(uint4*)&C[(size_t)gm*HD + w*64 + (ch+4)*8] = u1;
  }
}

// ---------------- BN finalize (bias folded here: stats are bias-free raw sums) ----------------
__global__ void k_bnfin(const float* __restrict__ cs, const float* __restrict__ bias,
                        const float* __restrict__ g, const float* __restrict__ be,
                        float* __restrict__ sc, float* __restrict__ sh){
  int c = threadIdx.x;
  float m0 = cs[c] * (1.0f/NN);
  float mean = m0 + bias[c];
  float var  = cs[HD + c] * (1.0f/NN) - m0*m0;
  float s = g[c] * rsqrtf(var + 1e-5f);
  sc[c] = s;
  sh[c] = be[c] - mean*s;
}

// ---------------- aggregation ----------------
__device__ __forceinline__ f4 act4(ushort4 uv, f4 s4, f4 t4, int ident){
  f4 u;
  u.x = bf2f(uv.x); u.y = bf2f(uv.y); u.z = bf2f(uv.z); u.w = bf2f(uv.w);
  if(!ident){
    u.x = fmaxf(fmaf(s4.x, u.x, t4.x), 0.f);
    u.y = fmaxf(fmaf(s4.y, u.y, t4.y), 0.f);
    u.z = fmaxf(fmaf(s4.z, u.z, t4.z), 0.f);
    u.w = fmaxf(fmaf(s4.w, u.w, t4.w), 0.f);
  }
  return u;
}

__global__ __launch_bounds__(256) void k_agg(const unsigned short* __restrict__ src,
    unsigned short* __restrict__ dst,
    const int* __restrict__ offs, const int* __restrict__ eidx,
    const float* __restrict__ eps, int l,
    const float* __restrict__ sc, const float* __restrict__ sh, int ident)
{
  int wv = threadIdx.x >> 6;
  int n = blockIdx.x*4 + wv;
  if(n >= NN) return;
  int lane = threadIdx.x & 63;
  int c = lane << 2;
  f4 s4 = (f4){0.f,0.f,0.f,0.f}, t4 = (f4){0.f,0.f,0.f,0.f};
  if(!ident){ s4 = *(const f4*)(sc + c); t4 = *(const f4*)(sh + c); }
  float ep = 1.f + eps[l];
  f4 a = act4(*(const ushort4*)(src + (size_t)n*HD + c), s4, t4, ident);
  f4 acc;
  acc.x = ep*a.x; acc.y = ep*a.y; acc.z = ep*a.z; acc.w = ep*a.w;
  int lo = offs[n], hi = offs[n+1];
  for(int base = lo; base < hi; base += 64){
    int rem = hi - base; if(rem > 64) rem = 64;
    int idx = 0;
    if(base + lane < hi) idx = eidx[base + lane];
    int j = 0;
    for(; j + 4 <= rem; j += 4){
      int s0 = __shfl(idx, j, 64),   s1 = __shfl(idx, j+1, 64);
      int s2 = __shfl(idx, j+2, 64), s3 = __shfl(idx, j+3, 64);
      ushort4 u0 = *(const ushort4*)(src + (size_t)s0*HD + c);
      ushort4 u1 = *(const ushort4*)(src + (size_t)s1*HD + c);
      ushort4 u2 = *(const ushort4*)(src + (size_t)s2*HD + c);
      ushort4 u3 = *(const ushort4*)(src + (size_t)s3*HD + c);
      f4 a0 = act4(u0, s4, t4, ident), a1 = act4(u1, s4, t4, ident);
      f4 a2 = act4(u2, s4, t4, ident), a3 = act4(u3, s4, t4, ident);
      acc.x += (a0.x + a1.x) + (a2.x + a3.x);
      acc.y += (a0.y + a1.y) + (a2.y + a3.y);
      acc.z += (a0.z + a1.z) + (a2.z + a3.z);
      acc.w += (a0.w + a1.w) + (a2.w + a3.w);
    }
    for(; j < rem; j++){
      int s0 = __shfl(idx, j, 64);
      f4 a0 = act4(*(const ushort4*)(src + (size_t)s0*HD + c), s4, t4, ident);
      acc.x += a0.x; acc.y += a0.y; acc.z += a0.z; acc.w += a0.w;
    }
  }
  ushort4 o;
  o.x = f2bf(acc.x); o.y = f2bf(acc.y); o.z = f2bf(acc.z); o.w = f2bf(acc.w);
  *(ushort4*)(dst + (size_t)n*HD + c) = o;
}

// ---------------- pooling ----------------
__device__ __forceinline__ int lowb(const int* __restrict__ arr, int n, int key){
  int lo = 0, hi = n;
  while(lo < hi){ int mid = (lo + hi) >> 1; if(arr[mid] < key) lo = mid + 1; else hi = mid; }
  return lo;
}

__global__ __launch_bounds__(256) void k_pool(const unsigned short* __restrict__ src,
    const int* __restrict__ batch,
    const float* __restrict__ sc, const float* __restrict__ sh, float* __restrict__ pooled)
{
  int wv = threadIdx.x >> 6;
  int g = blockIdx.x*4 + wv;
  if(g >= NG) return;
  int lane = threadIdx.x & 63;
  int c = lane << 2;
  int lo = lowb(batch, NN, g);
  int hi = lowb(batch, NN, g+1);
  f4 s4 = *(const f4*)(sc + c);
  f4 t4 = *(const f4*)(sh + c);
  f4 acc = (f4){0.f,0.f,0.f,0.f};
  for(int n=lo; n<hi; n++){
    ushort4 uv = *(const ushort4*)(src + (size_t)n*HD + c);
    acc.x += fmaxf(fmaf(s4.x, bf2f(uv.x), t4.x), 0.f);
    acc.y += fmaxf(fmaf(s4.y, bf2f(uv.y), t4.y), 0.f);
    acc.z += fmaxf(fmaf(s4.z, bf2f(uv.z), t4.z), 0.f);
    acc.w += fmaxf(fmaf(s4.w, bf2f(uv.w), t4.w), 0.f);
  }
  float inv = 1.0f / fmaxf((float)(hi - lo), 1.0f);
  acc.x *= inv; acc.y *= inv; acc.z *= inv; acc.w *= inv;
  *(f4*)(pooled + (size_t)g*HD + c) = acc;
}

// ---------------- head ----------------
__global__ __launch_bounds__(128) void k_head(const float* __restrict__ pooled,
    const float* __restrict__ W1, const float* __restrict__ b1,
    const float* __restrict__ W2, const float* __restrict__ b2, float* __restrict__ out)
{
  __shared__ float p[HD];
  __shared__ float red[2];
  int g = blockIdx.x, t = threadIdx.x;
  if(t < 64) *(f4*)&p[t*4] = *(const f4*)(pooled + (size_t)g*HD + t*4);
  __syncthreads();
  float s = b1[t];
  for(int k=0;k<HD;k++) s = fmaf(p[k], W1[k*128 + t], s);
  float o = fmaxf(s, 0.f) * W2[t];
  #pragma unroll
  for(int d=1; d<64; d<<=1) o += __shfl_xor(o, d, 64);
  if((t & 63) == 0) red[t>>6] = o;
  __syncthreads();
  if(t == 0) out[g] = red[0] + red[1] + b2[0];
}

// ---------------- launch ----------------
extern "C" void kernel_launch(void* const* d_in, const int* in_sizes, int n_in,
                              void* d_out, int out_size, void* d_ws, size_t ws_size,
                              hipStream_t stream) {
  const float* x    = (const float*)d_in[0];
  const int*   ei   = (const int*)  d_in[1];
  const int*   bat  = (const int*)  d_in[2];
  const float* inW  = (const float*)d_in[3];
  const float* inb  = (const float*)d_in[4];
  const float* W1   = (const float*)d_in[5];
  const float* b1   = (const float*)d_in[6];
  const float* g1   = (const float*)d_in[7];
  const float* be1  = (const float*)d_in[8];
  const float* W2   = (const float*)d_in[9];
  const float* b2   = (const float*)d_in[10];
  const float* g2   = (const float*)d_in[11];
  const float* be2  = (const float*)d_in[12];
  const float* eps  = (const float*)d_in[13];
  const float* hW1  = (const float*)d_in[14];
  const float* hb1  = (const float*)d_in[15];
  const float* hW2  = (const float*)d_in[16];
  const float* hb2  = (const float*)d_in[17];
  float* out = (float*)d_out;

  char* p = (char*)d_ws;
  auto alloc = [&](size_t bytes)->char*{
    char* r = p; p += (bytes + 255) & ~(size_t)255; return r;
  };
  unsigned short* B0 = (unsigned short*)alloc((size_t)MPAD*HD*2);
  unsigned short* B1 = (unsigned short*)alloc((size_t)MPAD*HD*2);
  unsigned short* Wtin = (unsigned short*)alloc((size_t)FINDIM*HD*2);
  unsigned short* Wt1  = (unsigned short*)alloc((size_t)NLAYER*HD*HD*2);
  unsigned short* Wt2  = (unsigned short*)alloc((size_t)NLAYER*HD*HD*2);
  int* counts  = (int*)alloc((size_t)NN*4);
  int* offsets = (int*)alloc((size_t)(NN+1)*4);
  int* cursor  = (int*)alloc((size_t)NN*4);
  int* eidx    = (int*)alloc((size_t)NE*4);
  int* partials= (int*)alloc(128*4);
  float* cs    = (float*)alloc(4*HD*4);
  float* bnp   = (float*)alloc(4*HD*4);
  float* pooled= (float*)alloc((size_t)NG*HD*4);

  // CSR build
  k_zero<<<(NN+255)/256, 256, 0, stream>>>(counts, NN);
  k_count<<<(NE+255)/256, 256, 0, stream>>>(ei, counts);
  int nb = (NN + 1023)/1024;
  k_scan_partial<<<nb, 256, 0, stream>>>(counts, partials);
  k_scan_tot<<<1, 128, 0, stream>>>(partials, offsets, nb);
  k_scan_final<<<nb, 256, 0, stream>>>(counts, partials, offsets, cursor);
  k_fill<<<(NE+255)/256, 256, 0, stream>>>(ei, cursor, eidx);

  // weights -> bf16 [n][k]
  k_wt<<<dim3((FINDIM*HD+255)/256, 1), 256, 0, stream>>>(inW, Wtin, FINDIM, HD);
  k_wt<<<dim3((HD*HD+255)/256, NLAYER), 256, 0, stream>>>(W1, Wt1, HD, HD);
  k_wt<<<dim3((HD*HD+255)/256, NLAYER), 256, 0, stream>>>(W2, Wt2, HD, HD);

  // zero pad rows of B1 once (B0's pad established by gemm_in epilogue)
  {
    int padInts = (MPAD - NN) * HD / 2;   // shorts/2
    k_zero<<<(padInts+255)/256, 256, 0, stream>>>((int*)(B1 + (size_t)NN*HD), padInts);
  }

  const int MB = MPAD/64;  // 1564 m-blocks
  k_gemm_in<<<MB, 256, 0, stream>>>(x, Wtin, inb, B0);

  float* sc1 = bnp, *sh1 = bnp + HD, *sc2 = bnp + 2*HD, *sh2 = bnp + 3*HD;
  unsigned short* hbuf = B0;
  unsigned short* tbuf = B1;
  for(int l=0; l<NLAYER; l++){
    k_zero<<<4, 256, 0, stream>>>((int*)cs, 4*HD);
    k_agg<<<(NN+3)/4, 256, 0, stream>>>(hbuf, tbuf, offsets, eidx, eps, l, sc2, sh2, l==0 ? 1 : 0);
    k_gemmp<0, false, true><<<MB, 256, 0, stream>>>(tbuf, Wt1 + (size_t)l*HD*HD, b1 + l*HD,
                                                    nullptr, nullptr, hbuf, cs);
    k_bnfin<<<1, HD, 0, stream>>>(cs, b1 + l*HD, g1 + l*HD, be1 + l*HD, sc1, sh1);
    k_gemmp<1, false, true><<<MB, 256, 0, stream>>>(hbuf, Wt2 + (size_t)l*HD*HD, b2 + l*HD,
                                                    sc1, sh1, tbuf, cs + 2*HD);
    k_bnfin<<<1, HD, 0, stream>>>(cs + 2*HD, b2 + l*HD, g2 + l*HD, be2 + l*HD, sc2, sh2);
    unsigned short* tmp = hbuf; hbuf = tbuf; tbuf = tmp;
  }

  k_pool<<<(NG+3)/4, 256, 0, stream>>>(hbuf, bat, sc2, sh2, pooled);
  k_head<<<NG, 128, 0, stream>>>(pooled, hW1, hb1, hW2, hb2, out);
}

// Round 7
// 902.431 us; speedup vs baseline: 1.2555x; 1.2043x over previous
//
#include <hip/hip_runtime.h>
#include <hip/hip_bf16.h>
#include <stdint.h>
#include <stddef.h>

#define NN 100000
#define NE 300000
#define FINDIM 128
#define HD 256
#define NG 4000
#define NLAYER 5
#define MPAD 100096   // multiple of 32; pad rows kept == 0.0f always
#define NT (MPAD/32)  // 3128 m-tiles of 32 rows
#define MG 384        // m-groups; grid = 2*MG

typedef __attribute__((ext_vector_type(8))) short bf8;
typedef __attribute__((ext_vector_type(4))) float f4;

__device__ __forceinline__ unsigned short f2bf(float f){
  union { float f; unsigned u; } uf; uf.f = f;
  unsigned r = uf.u + 0x7fffu + ((uf.u >> 16) & 1u);
  return (unsigned short)(r >> 16);
}
__device__ __forceinline__ float bf2f(unsigned short h){
  union { unsigned u; float f; } uf; uf.u = ((unsigned)h) << 16; return uf.f;
}

__device__ __forceinline__ void gload16(const void* g, void* l){
  __builtin_amdgcn_global_load_lds((const __attribute__((address_space(1))) void*)g,
                                   (__attribute__((address_space(3))) void*)l, 16, 0, 0);
}

// ---------------- zero fill ----------------
__global__ void k_zero(int* __restrict__ p, int n){
  int i = blockIdx.x*256 + threadIdx.x;
  if(i < n) p[i] = 0;
}

// ---------------- CSR build ----------------
__global__ void k_count(const int* __restrict__ ei, int* __restrict__ counts){
  int e = blockIdx.x*256 + threadIdx.x;
  if(e < NE) atomicAdd(&counts[ei[NE + e]], 1);
}

__global__ void k_scan_partial(const int* __restrict__ counts, int* __restrict__ partials){
  __shared__ int sw[4];
  int b = blockIdx.x, t = threadIdx.x;
  int base = b*1024 + t*4;
  int s = 0;
  #pragma unroll
  for(int j=0;j<4;j++){ int i = base+j; if(i < NN) s += counts[i]; }
  #pragma unroll
  for(int d=1; d<64; d<<=1) s += __shfl_xor(s, d, 64);
  if((t & 63) == 0) sw[t>>6] = s;
  __syncthreads();
  if(t == 0) partials[b] = sw[0]+sw[1]+sw[2]+sw[3];
}

__global__ void k_scan_tot(int* __restrict__ partials, int* __restrict__ offsets, int nb){
  __shared__ int sm[128];
  int t = threadIdx.x;
  int v = (t < nb) ? partials[t] : 0;
  sm[t] = v; __syncthreads();
  for(int d=1; d<128; d<<=1){
    int x = 0;
    if(t >= d) x = sm[t-d];
    __syncthreads();
    sm[t] += x;
    __syncthreads();
  }
  if(t < nb) partials[t] = sm[t] - v;   // exclusive
  if(t == 127) offsets[NN] = sm[127];   // total == NE
}

__global__ void k_scan_final(const int* __restrict__ counts, const int* __restrict__ partials,
                             int* __restrict__ offsets, int* __restrict__ cursor){
  __shared__ int wsum[4];
  int b = blockIdx.x, t = threadIdx.x;
  int base = b*1024 + t*4;
  int c[4]; int ts = 0;
  #pragma unroll
  for(int j=0;j<4;j++){ int i = base+j; c[j] = (i < NN) ? counts[i] : 0; ts += c[j]; }
  int lane = t & 63;
  int inc = ts;
  #pragma unroll
  for(int d=1; d<64; d<<=1){ int x = __shfl_up(inc, d, 64); if(lane >= d) inc += x; }
  if(lane == 63) wsum[t>>6] = inc;
  __syncthreads();
  int woff = 0;
  for(int w2=0; w2<(t>>6); w2++) woff += wsum[w2];
  int excl = partials[b] + woff + inc - ts;
  #pragma unroll
  for(int j=0;j<4;j++){
    int i = base+j;
    if(i < NN){ offsets[i] = excl; cursor[i] = excl; excl += c[j]; }
  }
}

__global__ void k_fill(const int* __restrict__ ei, int* __restrict__ cursor, int* __restrict__ eidx){
  int e = blockIdx.x*256 + threadIdx.x;
  if(e < NE){
    int d = ei[NE + e];
    int pos = atomicAdd(&cursor[d], 1);
    eidx[pos] = ei[e];
  }
}

// ---------------- weight transpose/convert ----------------
__global__ void k_wt(const float* __restrict__ src, unsigned short* __restrict__ dst, int K, int Ncols){
  int l = blockIdx.y;
  size_t base = (size_t)l * K * Ncols;
  int i = blockIdx.x*256 + threadIdx.x;
  if(i < K*Ncols){
    int k = i / Ncols, n = i % Ncols;
    dst[base + (size_t)n*K + k] = f2bf(src[base + i]);
  }
}

// ---------------- GEMM, B-in-registers: C[M,256](bf16) = act(A)[M,256] @ Bt^T + bias ----------------
// Grid 2*MG: nh = b&1 (n-half of 128), mg = b>>1. Block 256 thr / 4 waves; wave tile 32m x 32n.
// B frags (2 nf x 8 slabs = 64 VGPRs) loaded once from L2-resident weight. Inner loop: LDS+MFMA only.
// A staged per 32-row tile as one 16 KB DMA, double-buffered across the m-loop.
// Pad rows are zero; stats = raw col sums (bias folded in bnfin).
template<int TRANS, bool RELUOUT, bool STATS>
__global__ __launch_bounds__(256, 3) void k_gemmb(
    const unsigned short* __restrict__ A, const unsigned short* __restrict__ Bt,
    const float* __restrict__ bias, const float* __restrict__ preS,
    const float* __restrict__ preT, unsigned short* __restrict__ C,
    float* __restrict__ stats)
{
  __shared__ __align__(16) unsigned short As[2][8192];   // 2 x (32 rows x 256 k) = 32 KB
  __shared__ __align__(16) unsigned short Cs[4][1152];   // 4 waves x 32x36 = 9 KB
  __shared__ __align__(16) float SP[512];                // scale/shift for TRANS
  const int t = threadIdx.x;
  const int lane = t & 63, w = t >> 6;
  const int q = lane >> 4, ln = lane & 15;
  const int nh = blockIdx.x & 1;
  const int mg = blockIdx.x >> 1;
  const int nbase = nh*128 + w*32;

  if(TRANS){ SP[t] = preS[t]; SP[256 + t] = preT[t]; }

  // B fragments resident in registers
  bf8 bb[2][8];
  #pragma unroll
  for(int nf=0; nf<2; nf++)
    #pragma unroll
    for(int s=0; s<8; s++)
      bb[nf][s] = *(const bf8*)(Bt + (size_t)(nbase + nf*16 + ln)*HD + s*32 + q*8);

  float bv[2];
  #pragma unroll
  for(int nf=0; nf<2; nf++) bv[nf] = bias[nbase + nf*16 + ln];

  // A DMA: 32x256 tile, chunk at LDS pos p holds global chunk c = p ^ (row&7)
  auto issueA = [&](int mt, int b){
    const int m0 = mt*32;
    #pragma unroll
    for(int j=0; j<4; j++){
      int slot = j*256 + t;
      int row = slot >> 5, p = slot & 31;
      int c = p ^ (row & 7);
      gload16(A + (size_t)(m0 + row)*HD + c*8, &As[b][(j*256 + w*64)*8]);
    }
  };

  float sacc[2] = {0.f, 0.f}, ssacc[2] = {0.f, 0.f};

  int mt = mg, tc = 0;
  if(mt < NT) issueA(mt, 0);
  for(; mt < NT; mt += MG, tc++){
    __syncthreads();                     // DMA(tile tc) landed; buf[tc^1] free
    int mtn = mt + MG;
    if(mtn < NT) issueA(mtn, (tc+1)&1);
    const unsigned short* Ab = As[tc&1];
    const int m0 = mt*32;
    const bool padt = (m0 >= NN);        // NN%32==0: tiles are fully real or fully pad

    f4 acc[2][2];
    #pragma unroll
    for(int i=0;i<2;i++)
      #pragma unroll
      for(int j=0;j<2;j++) acc[i][j] = (f4){0.f,0.f,0.f,0.f};

    #pragma unroll
    for(int s=0; s<8; s++){
      bf8 af[2];
      #pragma unroll
      for(int mi=0; mi<2; mi++){
        int row = mi*16 + ln;
        int p = (s*4 + q) ^ (row & 7);
        af[mi] = *(const bf8*)&Ab[row*256 + p*8];
      }
      if(TRANS){
        f4 s0 = *(const f4*)&SP[s*32 + q*8];
        f4 s1 = *(const f4*)&SP[s*32 + q*8 + 4];
        f4 t0 = *(const f4*)&SP[256 + s*32 + q*8];
        f4 t1 = *(const f4*)&SP[256 + s*32 + q*8 + 4];
        float scv[8] = {s0.x,s0.y,s0.z,s0.w,s1.x,s1.y,s1.z,s1.w};
        float shv[8] = {t0.x,t0.y,t0.z,t0.w,t1.x,t1.y,t1.z,t1.w};
        #pragma unroll
        for(int mi=0; mi<2; mi++){
          #pragma unroll
          for(int j=0;j<8;j++){
            float v = bf2f((unsigned short)af[mi][j]);
            v = fmaxf(fmaf(scv[j], v, shv[j]), 0.f);
            af[mi][j] = (short)f2bf(v);
          }
        }
        if(padt){
          af[0] = (bf8){0,0,0,0,0,0,0,0};
          af[1] = (bf8){0,0,0,0,0,0,0,0};
        }
      }
      #pragma unroll
      for(int mi=0; mi<2; mi++)
        #pragma unroll
        for(int nf=0; nf<2; nf++)
          acc[mi][nf] = __builtin_amdgcn_mfma_f32_16x16x32_bf16(af[mi], bb[nf][s], acc[mi][nf], 0, 0, 0);
    }

    if(STATS){
      #pragma unroll
      for(int nf=0; nf<2; nf++)
        #pragma unroll
        for(int mi=0; mi<2; mi++)
          #pragma unroll
          for(int r=0; r<4; r++){
            float v = acc[mi][nf][r];
            sacc[nf] += v; ssacc[nf] = fmaf(v, v, ssacc[nf]);
          }
    }

    // epilogue: per-wave LDS transpose -> coalesced 16B row stores
    unsigned short* wsc = &Cs[w][0];     // 32 rows x 36
    #pragma unroll
    for(int mi=0; mi<2; mi++)
      #pragma unroll
      for(int nf=0; nf<2; nf++)
        #pragma unroll
        for(int r=0; r<4; r++){
          float v = acc[mi][nf][r] + bv[nf];
          if(RELUOUT) v = fmaxf(v, 0.f);
          if(padt) v = 0.f;
          wsc[(mi*16 + q*4 + r)*36 + nf*16 + ln] = f2bf(v);
        }
    int r2 = lane >> 1, ch = lane & 1;
    size_t cb = (size_t)(m0 + r2)*HD + nh*128 + w*32;
    uint4 u0 = *(const uint4*)&wsc[r2*36 + ch*8];
    uint4 u1 = *(const uint4*)&wsc[r2*36 + (ch+2)*8];
    *(uint4*)&C[cb + ch*8]     = u0;
    *(uint4*)&C[cb + (ch+2)*8] = u1;
  }

  if(STATS){
    #pragma unroll
    for(int nf=0; nf<2; nf++){
      float s = sacc[nf], ss = ssacc[nf];
      s  += __shfl_xor(s, 16, 64);  s  += __shfl_xor(s, 32, 64);
      ss += __shfl_xor(ss, 16, 64); ss += __shfl_xor(ss, 32, 64);
      if(q == 0){
        int gn = nbase + nf*16 + ln;
        atomicAdd(&stats[gn], s);
        atomicAdd(&stats[HD + gn], ss);
      }
    }
  }
}

// ---------------- input projection (f32 A, K=128), B-in-registers, single-buffered ----------------
__global__ __launch_bounds__(256, 3) void k_gemmb_in(
    const float* __restrict__ A, const unsigned short* __restrict__ Bt,
    const float* __restrict__ bias, unsigned short* __restrict__ C)
{
  __shared__ __align__(16) unsigned short As[4096];      // 32 rows x 128 k = 8 KB
  __shared__ __align__(16) unsigned short Cs[4][1152];
  const int t = threadIdx.x;
  const int lane = t & 63, w = t >> 6;
  const int q = lane >> 4, ln = lane & 15;
  const int nh = blockIdx.x & 1;
  const int mg = blockIdx.x >> 1;
  const int nbase = nh*128 + w*32;

  bf8 bb[2][4];
  #pragma unroll
  for(int nf=0; nf<2; nf++)
    #pragma unroll
    for(int s=0; s<4; s++)
      bb[nf][s] = *(const bf8*)(Bt + (size_t)(nbase + nf*16 + ln)*FINDIM + s*32 + q*8);

  float bv[2];
  #pragma unroll
  for(int nf=0; nf<2; nf++) bv[nf] = bias[nbase + nf*16 + ln];

  for(int mt = mg; mt < NT; mt += MG){
    const int m0 = mt*32;
    const bool padt = (m0 >= NN);
    // manual stage: 512 slots = 32 rows x 16 chunks, XOR-swizzled
    __syncthreads();
    #pragma unroll
    for(int j=0; j<2; j++){
      int slot = j*256 + t;
      int row = slot >> 4, p = slot & 15;
      int c = p ^ (row & 7);
      int gm = m0 + row;
      f4 v0 = (f4){0.f,0.f,0.f,0.f}, v1 = (f4){0.f,0.f,0.f,0.f};
      if(gm < NN){
        v0 = *(const f4*)&A[(size_t)gm*FINDIM + c*8];
        v1 = *(const f4*)&A[(size_t)gm*FINDIM + c*8 + 4];
      }
      ushort4 a0, a1;
      a0.x = f2bf(v0.x); a0.y = f2bf(v0.y); a0.z = f2bf(v0.z); a0.w = f2bf(v0.w);
      a1.x = f2bf(v1.x); a1.y = f2bf(v1.y); a1.z = f2bf(v1.z); a1.w = f2bf(v1.w);
      *(ushort4*)&As[row*128 + p*8]     = a0;
      *(ushort4*)&As[row*128 + p*8 + 4] = a1;
    }
    __syncthreads();

    f4 acc[2][2];
    #pragma unroll
    for(int i=0;i<2;i++)
      #pragma unroll
      for(int j=0;j<2;j++) acc[i][j] = (f4){0.f,0.f,0.f,0.f};

    #pragma unroll
    for(int s=0; s<4; s++){
      bf8 af[2];
      #pragma unroll
      for(int mi=0; mi<2; mi++){
        int row = mi*16 + ln;
        int p = (s*4 + q) ^ (row & 7);
        af[mi] = *(const bf8*)&As[row*128 + p*8];
      }
      #pragma unroll
      for(int mi=0; mi<2; mi++)
        #pragma unroll
        for(int nf=0; nf<2; nf++)
          acc[mi][nf] = __builtin_amdgcn_mfma_f32_16x16x32_bf16(af[mi], bb[nf][s], acc[mi][nf], 0, 0, 0);
    }

    unsigned short* wsc = &Cs[w][0];
    #pragma unroll
    for(int mi=0; mi<2; mi++)
      #pragma unroll
      for(int nf=0; nf<2; nf++)
        #pragma unroll
        for(int r=0; r<4; r++){
          float v = fmaxf(acc[mi][nf][r] + bv[nf], 0.f);
          if(padt) v = 0.f;
          wsc[(mi*16 + q*4 + r)*36 + nf*16 + ln] = f2bf(v);
        }
    int r2 = lane >> 1, ch = lane & 1;
    size_t cb = (size_t)(m0 + r2)*HD + nh*128 + w*32;
    uint4 u0 = *(const uint4*)&wsc[r2*36 + ch*8];
    uint4 u1 = *(const uint4*)&wsc[r2*36 + (ch+2)*8];
    *(uint4*)&C[cb + ch*8]     = u0;
    *(uint4*)&C[cb + (ch+2)*8] = u1;
  }
}

// ---------------- BN finalize (bias folded: stats are bias-free raw sums) ----------------
__global__ void k_bnfin(const float* __restrict__ cs, const float* __restrict__ bias,
                        const float* __restrict__ g, const float* __restrict__ be,
                        float* __restrict__ sc, float* __restrict__ sh){
  int c = threadIdx.x;
  float m0 = cs[c] * (1.0f/NN);
  float mean = m0 + bias[c];
  float var  = cs[HD + c] * (1.0f/NN) - m0*m0;
  float s = g[c] * rsqrtf(var + 1e-5f);
  sc[c] = s;
  sh[c] = be[c] - mean*s;
}

// ---------------- aggregation ----------------
__device__ __forceinline__ f4 act4(ushort4 uv, f4 s4, f4 t4, int ident){
  f4 u;
  u.x = bf2f(uv.x); u.y = bf2f(uv.y); u.z = bf2f(uv.z); u.w = bf2f(uv.w);
  if(!ident){
    u.x = fmaxf(fmaf(s4.x, u.x, t4.x), 0.f);
    u.y = fmaxf(fmaf(s4.y, u.y, t4.y), 0.f);
    u.z = fmaxf(fmaf(s4.z, u.z, t4.z), 0.f);
    u.w = fmaxf(fmaf(s4.w, u.w, t4.w), 0.f);
  }
  return u;
}

__global__ __launch_bounds__(256) void k_agg(const unsigned short* __restrict__ src,
    unsigned short* __restrict__ dst,
    const int* __restrict__ offs, const int* __restrict__ eidx,
    const float* __restrict__ eps, int l,
    const float* __restrict__ sc, const float* __restrict__ sh, int ident)
{
  int wv = threadIdx.x >> 6;
  int n = blockIdx.x*4 + wv;
  if(n >= NN) return;
  int lane = threadIdx.x & 63;
  int c = lane << 2;
  f4 s4 = (f4){0.f,0.f,0.f,0.f}, t4 = (f4){0.f,0.f,0.f,0.f};
  if(!ident){ s4 = *(const f4*)(sc + c); t4 = *(const f4*)(sh + c); }
  float ep = 1.f + eps[l];
  f4 a = act4(*(const ushort4*)(src + (size_t)n*HD + c), s4, t4, ident);
  f4 acc;
  acc.x = ep*a.x; acc.y = ep*a.y; acc.z = ep*a.z; acc.w = ep*a.w;
  int lo = offs[n], hi = offs[n+1];
  for(int base = lo; base < hi; base += 64){
    int rem = hi - base; if(rem > 64) rem = 64;
    int idx = 0;
    if(base + lane < hi) idx = eidx[base + lane];
    int j = 0;
    for(; j + 4 <= rem; j += 4){
      int s0 = __shfl(idx, j, 64),   s1 = __shfl(idx, j+1, 64);
      int s2 = __shfl(idx, j+2, 64), s3 = __shfl(idx, j+3, 64);
      ushort4 u0 = *(const ushort4*)(src + (size_t)s0*HD + c);
      ushort4 u1 = *(const ushort4*)(src + (size_t)s1*HD + c);
      ushort4 u2 = *(const ushort4*)(src + (size_t)s2*HD + c);
      ushort4 u3 = *(const ushort4*)(src + (size_t)s3*HD + c);
      f4 a0 = act4(u0, s4, t4, ident), a1 = act4(u1, s4, t4, ident);
      f4 a2 = act4(u2, s4, t4, ident), a3 = act4(u3, s4, t4, ident);
      acc.x += (a0.x + a1.x) + (a2.x + a3.x);
      acc.y += (a0.y + a1.y) + (a2.y + a3.y);
      acc.z += (a0.z + a1.z) + (a2.z + a3.z);
      acc.w += (a0.w + a1.w) + (a2.w + a3.w);
    }
    for(; j < rem; j++){
      int s0 = __shfl(idx, j, 64);
      f4 a0 = act4(*(const ushort4*)(src + (size_t)s0*HD + c), s4, t4, ident);
      acc.x += a0.x; acc.y += a0.y; acc.z += a0.z; acc.w += a0.w;
    }
  }
  ushort4 o;
  o.x = f2bf(acc.x); o.y = f2bf(acc.y); o.z = f2bf(acc.z); o.w = f2bf(acc.w);
  *(ushort4*)(dst + (size_t)n*HD + c) = o;
}

// ---------------- pooling ----------------
__device__ __forceinline__ int lowb(const int* __restrict__ arr, int n, int key){
  int lo = 0, hi = n;
  while(lo < hi){ int mid = (lo + hi) >> 1; if(arr[mid] < key) lo = mid + 1; else hi = mid; }
  return lo;
}

__global__ __launch_bounds__(256) void k_pool(const unsigned short* __restrict__ src,
    const int* __restrict__ batch,
    const float* __restrict__ sc, const float* __restrict__ sh, float* __restrict__ pooled)
{
  int wv = threadIdx.x >> 6;
  int g = blockIdx.x*4 + wv;
  if(g >= NG) return;
  int lane = threadIdx.x & 63;
  int c = lane << 2;
  int lo = lowb(batch, NN, g);
  int hi = lowb(batch, NN, g+1);
  f4 s4 = *(const f4*)(sc + c);
  f4 t4 = *(const f4*)(sh + c);
  f4 acc = (f4){0.f,0.f,0.f,0.f};
  for(int n=lo; n<hi; n++){
    ushort4 uv = *(const ushort4*)(src + (size_t)n*HD + c);
    acc.x += fmaxf(fmaf(s4.x, bf2f(uv.x), t4.x), 0.f);
    acc.y += fmaxf(fmaf(s4.y, bf2f(uv.y), t4.y), 0.f);
    acc.z += fmaxf(fmaf(s4.z, bf2f(uv.z), t4.z), 0.f);
    acc.w += fmaxf(fmaf(s4.w, bf2f(uv.w), t4.w), 0.f);
  }
  float inv = 1.0f / fmaxf((float)(hi - lo), 1.0f);
  acc.x *= inv; acc.y *= inv; acc.z *= inv; acc.w *= inv;
  *(f4*)(pooled + (size_t)g*HD + c) = acc;
}

// ---------------- head ----------------
__global__ __launch_bounds__(128) void k_head(const float* __restrict__ pooled,
    const float* __restrict__ W1, const float* __restrict__ b1,
    const float* __restrict__ W2, const float* __restrict__ b2, float* __restrict__ out)
{
  __shared__ float p[HD];
  __shared__ float red[2];
  int g = blockIdx.x, t = threadIdx.x;
  if(t < 64) *(f4*)&p[t*4] = *(const f4*)(pooled + (size_t)g*HD + t*4);
  __syncthreads();
  float s = b1[t];
  for(int k=0;k<HD;k++) s = fmaf(p[k], W1[k*128 + t], s);
  float o = fmaxf(s, 0.f) * W2[t];
  #pragma unroll
  for(int d=1; d<64; d<<=1) o += __shfl_xor(o, d, 64);
  if((t & 63) == 0) red[t>>6] = o;
  __syncthreads();
  if(t == 0) out[g] = red[0] + red[1] + b2[0];
}

// ---------------- launch ----------------
extern "C" void kernel_launch(void* const* d_in, const int* in_sizes, int n_in,
                              void* d_out, int out_size, void* d_ws, size_t ws_size,
                              hipStream_t stream) {
  const float* x    = (const float*)d_in[0];
  const int*   ei   = (const int*)  d_in[1];
  const int*   bat  = (const int*)  d_in[2];
  const float* inW  = (const float*)d_in[3];
  const float* inb  = (const float*)d_in[4];
  const float* W1   = (const float*)d_in[5];
  const float* b1   = (const float*)d_in[6];
  const float* g1   = (const float*)d_in[7];
  const float* be1  = (const float*)d_in[8];
  const float* W2   = (const float*)d_in[9];
  const float* b2   = (const float*)d_in[10];
  const float* g2   = (const float*)d_in[11];
  const float* be2  = (const float*)d_in[12];
  const float* eps  = (const float*)d_in[13];
  const float* hW1  = (const float*)d_in[14];
  const float* hb1  = (const float*)d_in[15];
  const float* hW2  = (const float*)d_in[16];
  const float* hb2  = (const float*)d_in[17];
  float* out = (float*)d_out;

  char* p = (char*)d_ws;
  auto alloc = [&](size_t bytes)->char*{
    char* r = p; p += (bytes + 255) & ~(size_t)255; return r;
  };
  unsigned short* B0 = (unsigned short*)alloc((size_t)MPAD*HD*2);
  unsigned short* B1 = (unsigned short*)alloc((size_t)MPAD*HD*2);
  unsigned short* Wtin = (unsigned short*)alloc((size_t)FINDIM*HD*2);
  unsigned short* Wt1  = (unsigned short*)alloc((size_t)NLAYER*HD*HD*2);
  unsigned short* Wt2  = (unsigned short*)alloc((size_t)NLAYER*HD*HD*2);
  int* counts  = (int*)alloc((size_t)NN*4);
  int* offsets = (int*)alloc((size_t)(NN+1)*4);
  int* cursor  = (int*)alloc((size_t)NN*4);
  int* eidx    = (int*)alloc((size_t)NE*4);
  int* partials= (int*)alloc(128*4);
  float* cs    = (float*)alloc(4*HD*4);
  float* bnp   = (float*)alloc(4*HD*4);
  float* pooled= (float*)alloc((size_t)NG*HD*4);

  // CSR build
  k_zero<<<(NN+255)/256, 256, 0, stream>>>(counts, NN);
  k_count<<<(NE+255)/256, 256, 0, stream>>>(ei, counts);
  int nb = (NN + 1023)/1024;
  k_scan_partial<<<nb, 256, 0, stream>>>(counts, partials);
  k_scan_tot<<<1, 128, 0, stream>>>(partials, offsets, nb);
  k_scan_final<<<nb, 256, 0, stream>>>(counts, partials, offsets, cursor);
  k_fill<<<(NE+255)/256, 256, 0, stream>>>(ei, cursor, eidx);

  // weights -> bf16 [n][k]
  k_wt<<<dim3((FINDIM*HD+255)/256, 1), 256, 0, stream>>>(inW, Wtin, FINDIM, HD);
  k_wt<<<dim3((HD*HD+255)/256, NLAYER), 256, 0, stream>>>(W1, Wt1, HD, HD);
  k_wt<<<dim3((HD*HD+255)/256, NLAYER), 256, 0, stream>>>(W2, Wt2, HD, HD);

  // zero pad rows of B1 once (B0's pad established by gemm_in epilogue)
  {
    int padInts = (MPAD - NN) * HD / 2;
    k_zero<<<(padInts+255)/256, 256, 0, stream>>>((int*)(B1 + (size_t)NN*HD), padInts);
  }

  k_gemmb_in<<<2*MG, 256, 0, stream>>>(x, Wtin, inb, B0);

  float* sc1 = bnp, *sh1 = bnp + HD, *sc2 = bnp + 2*HD, *sh2 = bnp + 3*HD;
  unsigned short* hbuf = B0;
  unsigned short* tbuf = B1;
  for(int l=0; l<NLAYER; l++){
    k_zero<<<4, 256, 0, stream>>>((int*)cs, 4*HD);
    k_agg<<<(NN+3)/4, 256, 0, stream>>>(hbuf, tbuf, offsets, eidx, eps, l, sc2, sh2, l==0 ? 1 : 0);
    k_gemmb<0, false, true><<<2*MG, 256, 0, stream>>>(tbuf, Wt1 + (size_t)l*HD*HD, b1 + l*HD,
                                                      nullptr, nullptr, hbuf, cs);
    k_bnfin<<<1, HD, 0, stream>>>(cs, b1 + l*HD, g1 + l*HD, be1 + l*HD, sc1, sh1);
    k_gemmb<1, false, true><<<2*MG, 256, 0, stream>>>(hbuf, Wt2 + (size_t)l*HD*HD, b2 + l*HD,
                                                      sc1, sh1, tbuf, cs + 2*HD);
    k_bnfin<<<1, HD, 0, stream>>>(cs + 2*HD, b2 + l*HD, g2 + l*HD, be2 + l*HD, sc2, sh2);
    unsigned short* tmp = hbuf; hbuf = tbuf; tbuf = tmp;
  }

  k_pool<<<(NG+3)/4, 256, 0, stream>>>(hbuf, bat, sc2, sh2, pooled);
  k_head<<<NG, 128, 0, stream>>>(pooled, hW1, hb1, hW2, hb2, out);
}

// Round 8
// 840.456 us; speedup vs baseline: 1.3481x; 1.0737x over previous
//
#include <hip/hip_runtime.h>
#include <hip/hip_bf16.h>
#include <stdint.h>
#include <stddef.h>

#define NN 100000
#define NE 300000
#define FINDIM 128
#define HD 256
#define NG 4000
#define NLAYER 5
#define MPAD 100096   // multiple of 32; pad rows kept == 0.0f always
#define NT (MPAD/32)  // 3128 m-tiles of 32 rows
#define MG 384        // m-groups; grid = 2*MG

typedef __attribute__((ext_vector_type(8))) short bf8;
typedef __attribute__((ext_vector_type(4))) float f4;

#define FENCE() __asm__ volatile("" ::: "memory")
#define WAITVM0() __asm__ volatile("s_waitcnt vmcnt(0)" ::: "memory")
#define WAITVM4() __asm__ volatile("s_waitcnt vmcnt(4)" ::: "memory")
#define WAITVM6() __asm__ volatile("s_waitcnt vmcnt(6)" ::: "memory")
#define WAITLGKM() __asm__ volatile("s_waitcnt lgkmcnt(0)" ::: "memory")
#define BARRIER() do { FENCE(); __builtin_amdgcn_s_barrier(); FENCE(); } while(0)

__device__ __forceinline__ unsigned short f2bf(float f){
  union { float f; unsigned u; } uf; uf.f = f;
  unsigned r = uf.u + 0x7fffu + ((uf.u >> 16) & 1u);
  return (unsigned short)(r >> 16);
}
__device__ __forceinline__ float bf2f(unsigned short h){
  union { unsigned u; float f; } uf; uf.u = ((unsigned)h) << 16; return uf.f;
}

__device__ __forceinline__ void gload16(const void* g, void* l){
  __builtin_amdgcn_global_load_lds((const __attribute__((address_space(1))) void*)g,
                                   (__attribute__((address_space(3))) void*)l, 16, 0, 0);
}

// ---------------- zero fill ----------------
__global__ void k_zero(int* __restrict__ p, int n){
  int i = blockIdx.x*256 + threadIdx.x;
  if(i < n) p[i] = 0;
}

// ---------------- CSR build ----------------
__global__ void k_count(const int* __restrict__ ei, int* __restrict__ counts){
  int e = blockIdx.x*256 + threadIdx.x;
  if(e < NE) atomicAdd(&counts[ei[NE + e]], 1);
}

__global__ void k_scan_partial(const int* __restrict__ counts, int* __restrict__ partials){
  __shared__ int sw[4];
  int b = blockIdx.x, t = threadIdx.x;
  int base = b*1024 + t*4;
  int s = 0;
  #pragma unroll
  for(int j=0;j<4;j++){ int i = base+j; if(i < NN) s += counts[i]; }
  #pragma unroll
  for(int d=1; d<64; d<<=1) s += __shfl_xor(s, d, 64);
  if((t & 63) == 0) sw[t>>6] = s;
  __syncthreads();
  if(t == 0) partials[b] = sw[0]+sw[1]+sw[2]+sw[3];
}

__global__ void k_scan_tot(int* __restrict__ partials, int* __restrict__ offsets, int nb){
  __shared__ int sm[128];
  int t = threadIdx.x;
  int v = (t < nb) ? partials[t] : 0;
  sm[t] = v; __syncthreads();
  for(int d=1; d<128; d<<=1){
    int x = 0;
    if(t >= d) x = sm[t-d];
    __syncthreads();
    sm[t] += x;
    __syncthreads();
  }
  if(t < nb) partials[t] = sm[t] - v;   // exclusive
  if(t == 127) offsets[NN] = sm[127];   // total == NE
}

__global__ void k_scan_final(const int* __restrict__ counts, const int* __restrict__ partials,
                             int* __restrict__ offsets, int* __restrict__ cursor){
  __shared__ int wsum[4];
  int b = blockIdx.x, t = threadIdx.x;
  int base = b*1024 + t*4;
  int c[4]; int ts = 0;
  #pragma unroll
  for(int j=0;j<4;j++){ int i = base+j; c[j] = (i < NN) ? counts[i] : 0; ts += c[j]; }
  int lane = t & 63;
  int inc = ts;
  #pragma unroll
  for(int d=1; d<64; d<<=1){ int x = __shfl_up(inc, d, 64); if(lane >= d) inc += x; }
  if(lane == 63) wsum[t>>6] = inc;
  __syncthreads();
  int woff = 0;
  for(int w2=0; w2<(t>>6); w2++) woff += wsum[w2];
  int excl = partials[b] + woff + inc - ts;
  #pragma unroll
  for(int j=0;j<4;j++){
    int i = base+j;
    if(i < NN){ offsets[i] = excl; cursor[i] = excl; excl += c[j]; }
  }
}

__global__ void k_fill(const int* __restrict__ ei, int* __restrict__ cursor, int* __restrict__ eidx){
  int e = blockIdx.x*256 + threadIdx.x;
  if(e < NE){
    int d = ei[NE + e];
    int pos = atomicAdd(&cursor[d], 1);
    eidx[pos] = ei[e];
  }
}

// ---------------- weight transpose/convert ----------------
__global__ void k_wt(const float* __restrict__ src, unsigned short* __restrict__ dst, int K, int Ncols){
  int l = blockIdx.y;
  size_t base = (size_t)l * K * Ncols;
  int i = blockIdx.x*256 + threadIdx.x;
  if(i < K*Ncols){
    int k = i / Ncols, n = i % Ncols;
    dst[base + (size_t)n*K + k] = f2bf(src[base + i]);
  }
}

// ---------------- GEMM, B-in-regs + manual per-tile DMA pipeline ----------------
// Grid 2*MG: nh = b&1, mg = b>>1. Block 256 thr / 4 waves; wave tile 32m x 32n.
// A staged per 32x256 tile (16 KB, 4 gload16/wave), 2 buffers, raw-barrier pipeline:
// WAITVM keeps next tile's DMA in flight across barriers (never drains to 0 mid-loop).
// TRANS: one-pass in-LDS BN transform after DMA lands (not per-frag-use).
template<int TRANS, bool RELUOUT, bool STATS>
__global__ __launch_bounds__(256, 3) void k_gemmb(
    const unsigned short* __restrict__ A, const unsigned short* __restrict__ Bt,
    const float* __restrict__ bias, const float* __restrict__ preS,
    const float* __restrict__ preT, unsigned short* __restrict__ C,
    float* __restrict__ stats)
{
  __shared__ __align__(16) unsigned short As[2][8192];   // 32 KB
  __shared__ __align__(16) unsigned short Cs[4][1152];   // 9 KB
  __shared__ __align__(16) float SP[512];                // 2 KB
  const int t = threadIdx.x;
  const int lane = t & 63, w = t >> 6;
  const int q = lane >> 4, ln = lane & 15;
  const int nh = blockIdx.x & 1;
  const int mg = blockIdx.x >> 1;
  const int nbase = nh*128 + w*32;

  if(TRANS){ SP[t] = preS[t]; SP[256 + t] = preT[t]; WAITLGKM(); }

  // B fragments resident in registers (L2-resident 128 KB weight)
  bf8 bb[2][8];
  #pragma unroll
  for(int nf=0; nf<2; nf++)
    #pragma unroll
    for(int s=0; s<8; s++)
      bb[nf][s] = *(const bf8*)(Bt + (size_t)(nbase + nf*16 + ln)*HD + s*32 + q*8);

  float bv[2];
  #pragma unroll
  for(int nf=0; nf<2; nf++) bv[nf] = bias[nbase + nf*16 + ln];

  auto issueA = [&](int mt, int b){
    const int m0 = mt*32;
    #pragma unroll
    for(int j=0; j<4; j++){
      int slot = j*256 + t;
      int row = slot >> 5, p = slot & 31;
      int c = p ^ (row & 7);
      gload16(A + (size_t)(m0 + row)*HD + c*8, &As[b][(j*256 + w*64)*8]);
    }
  };

  float sacc[2] = {0.f, 0.f}, ssacc[2] = {0.f, 0.f};

  issueA(mg, 0);
  issueA(mg + MG, 1);           // mg+MG < NT always (mg<384, NT=3128)

  int tc = 0;
  for(int mt = mg; mt < NT; mt += MG, tc++){
    const bool last = (mt + MG >= NT);
    // wait DMA(tc) done, keep later DMA + prior stores in flight
    if(last)           WAITVM0();
    else if(tc == 0)   WAITVM4();
    else               WAITVM6();
    BARRIER();                          // all waves have tile tc in LDS

    unsigned short* Ab = &As[tc&1][0];
    const int m0 = mt*32;
    const bool padt = (m0 >= NN);

    if(TRANS){
      // one-pass in-LDS BN+ReLU transform (or zero pad tiles)
      #pragma unroll
      for(int j=0; j<4; j++){
        int slot = j*256 + t;
        if(padt){
          *(uint4*)&Ab[slot*8] = (uint4){0u,0u,0u,0u};
        } else {
          int row = slot >> 5, p = slot & 31;
          int c = p ^ (row & 7);
          uint4 u = *(const uint4*)&Ab[slot*8];
          f4 s0 = *(const f4*)&SP[c*8];
          f4 s1 = *(const f4*)&SP[c*8 + 4];
          f4 t0 = *(const f4*)&SP[256 + c*8];
          f4 t1 = *(const f4*)&SP[256 + c*8 + 4];
          float scv[8] = {s0.x,s0.y,s0.z,s0.w,s1.x,s1.y,s1.z,s1.w};
          float shv[8] = {t0.x,t0.y,t0.z,t0.w,t1.x,t1.y,t1.z,t1.w};
          unsigned short* us = (unsigned short*)&u;
          #pragma unroll
          for(int e=0; e<8; e++){
            float v = bf2f(us[e]);
            v = fmaxf(fmaf(scv[e], v, shv[e]), 0.f);
            us[e] = f2bf(v);
          }
          *(uint4*)&Ab[slot*8] = u;
        }
      }
      WAITLGKM();
      BARRIER();                        // transformed tile visible to all waves
    }

    f4 acc[2][2];
    #pragma unroll
    for(int i=0;i<2;i++)
      #pragma unroll
      for(int j=0;j<2;j++) acc[i][j] = (f4){0.f,0.f,0.f,0.f};

    #pragma unroll
    for(int s=0; s<8; s++){
      bf8 af[2];
      #pragma unroll
      for(int mi=0; mi<2; mi++){
        int row = mi*16 + ln;
        int p = (s*4 + q) ^ (row & 7);
        af[mi] = *(const bf8*)&Ab[row*256 + p*8];
      }
      #pragma unroll
      for(int mi=0; mi<2; mi++)
        #pragma unroll
        for(int nf=0; nf<2; nf++)
          acc[mi][nf] = __builtin_amdgcn_mfma_f32_16x16x32_bf16(af[mi], bb[nf][s], acc[mi][nf], 0, 0, 0);
    }

    if(STATS){
      #pragma unroll
      for(int nf=0; nf<2; nf++)
        #pragma unroll
        for(int mi=0; mi<2; mi++)
          #pragma unroll
          for(int r=0; r<4; r++){
            float v = acc[mi][nf][r];
            sacc[nf] += v; ssacc[nf] = fmaf(v, v, ssacc[nf]);
          }
    }

    // epilogue: per-wave LDS transpose -> coalesced 16B row stores
    unsigned short* wsc = &Cs[w][0];     // 32 rows x 36
    #pragma unroll
    for(int mi=0; mi<2; mi++)
      #pragma unroll
      for(int nf=0; nf<2; nf++)
        #pragma unroll
        for(int r=0; r<4; r++){
          float v = acc[mi][nf][r] + bv[nf];
          if(RELUOUT) v = fmaxf(v, 0.f);
          if(padt) v = 0.f;
          wsc[(mi*16 + q*4 + r)*36 + nf*16 + ln] = f2bf(v);
        }
    {
      int r2 = lane >> 1, ch = lane & 1;
      size_t cb = (size_t)(m0 + r2)*HD + nh*128 + w*32;
      uint4 u0 = *(const uint4*)&wsc[r2*36 + ch*8];
      uint4 u1 = *(const uint4*)&wsc[r2*36 + (ch+2)*8];
      *(uint4*)&C[cb + ch*8]     = u0;
      *(uint4*)&C[cb + (ch+2)*8] = u1;
    }

    // all waves done reading buf[tc&1] -> safe to re-DMA it
    WAITLGKM();
    BARRIER();
    if(mt + 2*MG < NT) issueA(mt + 2*MG, tc&1);
  }

  if(STATS){
    #pragma unroll
    for(int nf=0; nf<2; nf++){
      float s = sacc[nf], ss = ssacc[nf];
      s  += __shfl_xor(s, 16, 64);  s  += __shfl_xor(s, 32, 64);
      ss += __shfl_xor(ss, 16, 64); ss += __shfl_xor(ss, 32, 64);
      if(q == 0){
        int gn = nbase + nf*16 + ln;
        atomicAdd(&stats[gn], s);
        atomicAdd(&stats[HD + gn], ss);
      }
    }
  }
}

// ---------------- input projection (f32 A, K=128), B-in-registers ----------------
__global__ __launch_bounds__(256, 3) void k_gemmb_in(
    const float* __restrict__ A, const unsigned short* __restrict__ Bt,
    const float* __restrict__ bias, unsigned short* __restrict__ C)
{
  __shared__ __align__(16) unsigned short As[4096];      // 32 rows x 128 k = 8 KB
  __shared__ __align__(16) unsigned short Cs[4][1152];
  const int t = threadIdx.x;
  const int lane = t & 63, w = t >> 6;
  const int q = lane >> 4, ln = lane & 15;
  const int nh = blockIdx.x & 1;
  const int mg = blockIdx.x >> 1;
  const int nbase = nh*128 + w*32;

  bf8 bb[2][4];
  #pragma unroll
  for(int nf=0; nf<2; nf++)
    #pragma unroll
    for(int s=0; s<4; s++)
      bb[nf][s] = *(const bf8*)(Bt + (size_t)(nbase + nf*16 + ln)*FINDIM + s*32 + q*8);

  float bv[2];
  #pragma unroll
  for(int nf=0; nf<2; nf++) bv[nf] = bias[nbase + nf*16 + ln];

  for(int mt = mg; mt < NT; mt += MG){
    const int m0 = mt*32;
    const bool padt = (m0 >= NN);
    __syncthreads();
    #pragma unroll
    for(int j=0; j<2; j++){
      int slot = j*256 + t;
      int row = slot >> 4, p = slot & 15;
      int c = p ^ (row & 7);
      int gm = m0 + row;
      f4 v0 = (f4){0.f,0.f,0.f,0.f}, v1 = (f4){0.f,0.f,0.f,0.f};
      if(gm < NN){
        v0 = *(const f4*)&A[(size_t)gm*FINDIM + c*8];
        v1 = *(const f4*)&A[(size_t)gm*FINDIM + c*8 + 4];
      }
      ushort4 a0, a1;
      a0.x = f2bf(v0.x); a0.y = f2bf(v0.y); a0.z = f2bf(v0.z); a0.w = f2bf(v0.w);
      a1.x = f2bf(v1.x); a1.y = f2bf(v1.y); a1.z = f2bf(v1.z); a1.w = f2bf(v1.w);
      *(ushort4*)&As[row*128 + p*8]     = a0;
      *(ushort4*)&As[row*128 + p*8 + 4] = a1;
    }
    __syncthreads();

    f4 acc[2][2];
    #pragma unroll
    for(int i=0;i<2;i++)
      #pragma unroll
      for(int j=0;j<2;j++) acc[i][j] = (f4){0.f,0.f,0.f,0.f};

    #pragma unroll
    for(int s=0; s<4; s++){
      bf8 af[2];
      #pragma unroll
      for(int mi=0; mi<2; mi++){
        int row = mi*16 + ln;
        int p = (s*4 + q) ^ (row & 7);
        af[mi] = *(const bf8*)&As[row*128 + p*8];
      }
      #pragma unroll
      for(int mi=0; mi<2; mi++)
        #pragma unroll
        for(int nf=0; nf<2; nf++)
          acc[mi][nf] = __builtin_amdgcn_mfma_f32_16x16x32_bf16(af[mi], bb[nf][s], acc[mi][nf], 0, 0, 0);
    }

    unsigned short* wsc = &Cs[w][0];
    #pragma unroll
    for(int mi=0; mi<2; mi++)
      #pragma unroll
      for(int nf=0; nf<2; nf++)
        #pragma unroll
        for(int r=0; r<4; r++){
          float v = fmaxf(acc[mi][nf][r] + bv[nf], 0.f);
          if(padt) v = 0.f;
          wsc[(mi*16 + q*4 + r)*36 + nf*16 + ln] = f2bf(v);
        }
    int r2 = lane >> 1, ch = lane & 1;
    size_t cb = (size_t)(m0 + r2)*HD + nh*128 + w*32;
    uint4 u0 = *(const uint4*)&wsc[r2*36 + ch*8];
    uint4 u1 = *(const uint4*)&wsc[r2*36 + (ch+2)*8];
    *(uint4*)&C[cb + ch*8]     = u0;
    *(uint4*)&C[cb + (ch+2)*8] = u1;
  }
}

// ---------------- BN finalize (bias folded: stats are bias-free raw sums) ----------------
__global__ void k_bnfin(const float* __restrict__ cs, const float* __restrict__ bias,
                        const float* __restrict__ g, const float* __restrict__ be,
                        float* __restrict__ sc, float* __restrict__ sh){
  int c = threadIdx.x;
  float m0 = cs[c] * (1.0f/NN);
  float mean = m0 + bias[c];
  float var  = cs[HD + c] * (1.0f/NN) - m0*m0;
  float s = g[c] * rsqrtf(var + 1e-5f);
  sc[c] = s;
  sh[c] = be[c] - mean*s;
}

// ---------------- aggregation ----------------
__device__ __forceinline__ f4 act4(ushort4 uv, f4 s4, f4 t4, int ident){
  f4 u;
  u.x = bf2f(uv.x); u.y = bf2f(uv.y); u.z = bf2f(uv.z); u.w = bf2f(uv.w);
  if(!ident){
    u.x = fmaxf(fmaf(s4.x, u.x, t4.x), 0.f);
    u.y = fmaxf(fmaf(s4.y, u.y, t4.y), 0.f);
    u.z = fmaxf(fmaf(s4.z, u.z, t4.z), 0.f);
    u.w = fmaxf(fmaf(s4.w, u.w, t4.w), 0.f);
  }
  return u;
}

__global__ __launch_bounds__(256) void k_agg(const unsigned short* __restrict__ src,
    unsigned short* __restrict__ dst,
    const int* __restrict__ offs, const int* __restrict__ eidx,
    const float* __restrict__ eps, int l,
    const float* __restrict__ sc, const float* __restrict__ sh, int ident)
{
  int wv = threadIdx.x >> 6;
  int n = blockIdx.x*4 + wv;
  if(n >= NN) return;
  int lane = threadIdx.x & 63;
  int c = lane << 2;
  f4 s4 = (f4){0.f,0.f,0.f,0.f}, t4 = (f4){0.f,0.f,0.f,0.f};
  if(!ident){ s4 = *(const f4*)(sc + c); t4 = *(const f4*)(sh + c); }
  float ep = 1.f + eps[l];
  f4 a = act4(*(const ushort4*)(src + (size_t)n*HD + c), s4, t4, ident);
  f4 acc;
  acc.x = ep*a.x; acc.y = ep*a.y; acc.z = ep*a.z; acc.w = ep*a.w;
  int lo = offs[n], hi = offs[n+1];
  for(int base = lo; base < hi; base += 64){
    int rem = hi - base; if(rem > 64) rem = 64;
    int idx = 0;
    if(base + lane < hi) idx = eidx[base + lane];
    int j = 0;
    for(; j + 4 <= rem; j += 4){
      int s0 = __shfl(idx, j, 64),   s1 = __shfl(idx, j+1, 64);
      int s2 = __shfl(idx, j+2, 64), s3 = __shfl(idx, j+3, 64);
      ushort4 u0 = *(const ushort4*)(src + (size_t)s0*HD + c);
      ushort4 u1 = *(const ushort4*)(src + (size_t)s1*HD + c);
      ushort4 u2 = *(const ushort4*)(src + (size_t)s2*HD + c);
      ushort4 u3 = *(const ushort4*)(src + (size_t)s3*HD + c);
      f4 a0 = act4(u0, s4, t4, ident), a1 = act4(u1, s4, t4, ident);
      f4 a2 = act4(u2, s4, t4, ident), a3 = act4(u3, s4, t4, ident);
      acc.x += (a0.x + a1.x) + (a2.x + a3.x);
      acc.y += (a0.y + a1.y) + (a2.y + a3.y);
      acc.z += (a0.z + a1.z) + (a2.z + a3.z);
      acc.w += (a0.w + a1.w) + (a2.w + a3.w);
    }
    for(; j < rem; j++){
      int s0 = __shfl(idx, j, 64);
      f4 a0 = act4(*(const ushort4*)(src + (size_t)s0*HD + c), s4, t4, ident);
      acc.x += a0.x; acc.y += a0.y; acc.z += a0.z; acc.w += a0.w;
    }
  }
  ushort4 o;
  o.x = f2bf(acc.x); o.y = f2bf(acc.y); o.z = f2bf(acc.z); o.w = f2bf(acc.w);
  *(ushort4*)(dst + (size_t)n*HD + c) = o;
}

// ---------------- pooling ----------------
__device__ __forceinline__ int lowb(const int* __restrict__ arr, int n, int key){
  int lo = 0, hi = n;
  while(lo < hi){ int mid = (lo + hi) >> 1; if(arr[mid] < key) lo = mid + 1; else hi = mid; }
  return lo;
}

__global__ __launch_bounds__(256) void k_pool(const unsigned short* __restrict__ src,
    const int* __restrict__ batch,
    const float* __restrict__ sc, const float* __restrict__ sh, float* __restrict__ pooled)
{
  int wv = threadIdx.x >> 6;
  int g = blockIdx.x*4 + wv;
  if(g >= NG) return;
  int lane = threadIdx.x & 63;
  int c = lane << 2;
  int lo = lowb(batch, NN, g);
  int hi = lowb(batch, NN, g+1);
  f4 s4 = *(const f4*)(sc + c);
  f4 t4 = *(const f4*)(sh + c);
  f4 acc = (f4){0.f,0.f,0.f,0.f};
  for(int n=lo; n<hi; n++){
    ushort4 uv = *(const ushort4*)(src + (size_t)n*HD + c);
    acc.x += fmaxf(fmaf(s4.x, bf2f(uv.x), t4.x), 0.f);
    acc.y += fmaxf(fmaf(s4.y, bf2f(uv.y), t4.y), 0.f);
    acc.z += fmaxf(fmaf(s4.z, bf2f(uv.z), t4.z), 0.f);
    acc.w += fmaxf(fmaf(s4.w, bf2f(uv.w), t4.w), 0.f);
  }
  float inv = 1.0f / fmaxf((float)(hi - lo), 1.0f);
  acc.x *= inv; acc.y *= inv; acc.z *= inv; acc.w *= inv;
  *(f4*)(pooled + (size_t)g*HD + c) = acc;
}

// ---------------- head ----------------
__global__ __launch_bounds__(128) void k_head(const float* __restrict__ pooled,
    const float* __restrict__ W1, const float* __restrict__ b1,
    const float* __restrict__ W2, const float* __restrict__ b2, float* __restrict__ out)
{
  __shared__ float p[HD];
  __shared__ float red[2];
  int g = blockIdx.x, t = threadIdx.x;
  if(t < 64) *(f4*)&p[t*4] = *(const f4*)(pooled + (size_t)g*HD + t*4);
  __syncthreads();
  float s = b1[t];
  for(int k=0;k<HD;k++) s = fmaf(p[k], W1[k*128 + t], s);
  float o = fmaxf(s, 0.f) * W2[t];
  #pragma unroll
  for(int d=1; d<64; d<<=1) o += __shfl_xor(o, d, 64);
  if((t & 63) == 0) red[t>>6] = o;
  __syncthreads();
  if(t == 0) out[g] = red[0] + red[1] + b2[0];
}

// ---------------- launch ----------------
extern "C" void kernel_launch(void* const* d_in, const int* in_sizes, int n_in,
                              void* d_out, int out_size, void* d_ws, size_t ws_size,
                              hipStream_t stream) {
  const float* x    = (const float*)d_in[0];
  const int*   ei   = (const int*)  d_in[1];
  const int*   bat  = (const int*)  d_in[2];
  const float* inW  = (const float*)d_in[3];
  const float* inb  = (const float*)d_in[4];
  const float* W1   = (const float*)d_in[5];
  const float* b1   = (const float*)d_in[6];
  const float* g1   = (const float*)d_in[7];
  const float* be1  = (const float*)d_in[8];
  const float* W2   = (const float*)d_in[9];
  const float* b2   = (const float*)d_in[10];
  const float* g2   = (const float*)d_in[11];
  const float* be2  = (const float*)d_in[12];
  const float* eps  = (const float*)d_in[13];
  const float* hW1  = (const float*)d_in[14];
  const float* hb1  = (const float*)d_in[15];
  const float* hW2  = (const float*)d_in[16];
  const float* hb2  = (const float*)d_in[17];
  float* out = (float*)d_out;

  char* p = (char*)d_ws;
  auto alloc = [&](size_t bytes)->char*{
    char* r = p; p += (bytes + 255) & ~(size_t)255; return r;
  };
  unsigned short* B0 = (unsigned short*)alloc((size_t)MPAD*HD*2);
  unsigned short* B1 = (unsigned short*)alloc((size_t)MPAD*HD*2);
  unsigned short* Wtin = (unsigned short*)alloc((size_t)FINDIM*HD*2);
  unsigned short* Wt1  = (unsigned short*)alloc((size_t)NLAYER*HD*HD*2);
  unsigned short* Wt2  = (unsigned short*)alloc((size_t)NLAYER*HD*HD*2);
  int* counts  = (int*)alloc((size_t)NN*4);
  int* offsets = (int*)alloc((size_t)(NN+1)*4);
  int* cursor  = (int*)alloc((size_t)NN*4);
  int* eidx    = (int*)alloc((size_t)NE*4);
  int* partials= (int*)alloc(128*4);
  float* cs    = (float*)alloc(4*HD*4);
  float* bnp   = (float*)alloc(4*HD*4);
  float* pooled= (float*)alloc((size_t)NG*HD*4);

  // CSR build
  k_zero<<<(NN+255)/256, 256, 0, stream>>>(counts, NN);
  k_count<<<(NE+255)/256, 256, 0, stream>>>(ei, counts);
  int nb = (NN + 1023)/1024;
  k_scan_partial<<<nb, 256, 0, stream>>>(counts, partials);
  k_scan_tot<<<1, 128, 0, stream>>>(partials, offsets, nb);
  k_scan_final<<<nb, 256, 0, stream>>>(counts, partials, offsets, cursor);
  k_fill<<<(NE+255)/256, 256, 0, stream>>>(ei, cursor, eidx);

  // weights -> bf16 [n][k]
  k_wt<<<dim3((FINDIM*HD+255)/256, 1), 256, 0, stream>>>(inW, Wtin, FINDIM, HD);
  k_wt<<<dim3((HD*HD+255)/256, NLAYER), 256, 0, stream>>>(W1, Wt1, HD, HD);
  k_wt<<<dim3((HD*HD+255)/256, NLAYER), 256, 0, stream>>>(W2, Wt2, HD, HD);

  // zero pad rows of B1 once (B0's pad established by gemm_in epilogue)
  {
    int padInts = (MPAD - NN) * HD / 2;
    k_zero<<<(padInts+255)/256, 256, 0, stream>>>((int*)(B1 + (size_t)NN*HD), padInts);
  }

  k_gemmb_in<<<2*MG, 256, 0, stream>>>(x, Wtin, inb, B0);

  float* sc1 = bnp, *sh1 = bnp + HD, *sc2 = bnp + 2*HD, *sh2 = bnp + 3*HD;
  unsigned short* hbuf = B0;
  unsigned short* tbuf = B1;
  for(int l=0; l<NLAYER; l++){
    k_zero<<<4, 256, 0, stream>>>((int*)cs, 4*HD);
    k_agg<<<(NN+3)/4, 256, 0, stream>>>(hbuf, tbuf, offsets, eidx, eps, l, sc2, sh2, l==0 ? 1 : 0);
    k_gemmb<0, false, true><<<2*MG, 256, 0, stream>>>(tbuf, Wt1 + (size_t)l*HD*HD, b1 + l*HD,
                                                      nullptr, nullptr, hbuf, cs);
    k_bnfin<<<1, HD, 0, stream>>>(cs, b1 + l*HD, g1 + l*HD, be1 + l*HD, sc1, sh1);
    k_gemmb<1, false, true><<<2*MG, 256, 0, stream>>>(hbuf, Wt2 + (size_t)l*HD*HD, b2 + l*HD,
                                                      sc1, sh1, tbuf, cs + 2*HD);
    k_bnfin<<<1, HD, 0, stream>>>(cs + 2*HD, b2 + l*HD, g2 + l*HD, be2 + l*HD, sc2, sh2);
    unsigned short* tmp = hbuf; hbuf = tbuf; tbuf = tmp;
  }

  k_pool<<<(NG+3)/4, 256, 0, stream>>>(hbuf, bat, sc2, sh2, pooled);
  k_head<<<NG, 128, 0, stream>>>(pooled, hW1, hb1, hW2, hb2, out);
}